// Round 1
// baseline (1152.329 us; speedup 1.0000x reference)
//
#include <hip/hip_runtime.h>

#define NNODES 100000
#define NEDGES 3200000
#define F_IN   256
#define F_HID  32
#define F_OUT  16

// ---------------- degree / norm ----------------

__global__ void k_init_deg(float* __restrict__ deg) {
    int i = blockIdx.x * blockDim.x + threadIdx.x;
    if (i < NNODES) deg[i] = 1.0f;  // self-loop
}

__global__ void k_count_deg(const int* __restrict__ dst, float* __restrict__ deg) {
    int e = blockIdx.x * blockDim.x + threadIdx.x;
    if (e < NEDGES) unsafeAtomicAdd(&deg[dst[e]], 1.0f);
}

__global__ void k_dinv(float* __restrict__ deg) {
    int i = blockIdx.x * blockDim.x + threadIdx.x;
    if (i < NNODES) deg[i] = rsqrtf(deg[i]);  // in-place: deg -> dinv
}

__global__ void k_edge_w(const int* __restrict__ src, const int* __restrict__ dst,
                         const float* __restrict__ dinv, float* __restrict__ w) {
    int e = blockIdx.x * blockDim.x + threadIdx.x;
    if (e < NEDGES) w[e] = dinv[src[e]] * dinv[dst[e]];
}

// ---------------- layer-1 GEMM: h1 = x @ W1 ; agg1 = h1*dinv^2 (self loop) --------
// block = 256 threads; f = tx&31 (output feature), each 32-lane group does 4 rows.
// W1 (256x32 = 32KB) staged in LDS; 4 rows/thread amortizes the LDS read per FMA.

__global__ __launch_bounds__(256) void k_gemm1(
        const float* __restrict__ x, const float* __restrict__ W1,
        const float* __restrict__ dinv,
        float* __restrict__ h1, float* __restrict__ agg1) {
    __shared__ float ldsW[F_IN * F_HID];
    int tx = threadIdx.x;
    for (int idx = tx; idx < F_IN * F_HID; idx += 256) ldsW[idx] = W1[idx];
    __syncthreads();

    int f = tx & 31;
    int rg = tx >> 5;                       // 0..7
    int row0 = blockIdx.x * 32 + rg * 4;    // 32 rows per block, grid is exact
    const float* xr = x + (size_t)row0 * F_IN;

    float acc0 = 0.f, acc1 = 0.f, acc2 = 0.f, acc3 = 0.f;
    #pragma unroll 8
    for (int k = 0; k < F_IN; ++k) {
        float wv = ldsW[k * F_HID + f];
        acc0 = fmaf(xr[k],            wv, acc0);
        acc1 = fmaf(xr[F_IN + k],     wv, acc1);
        acc2 = fmaf(xr[2 * F_IN + k], wv, acc2);
        acc3 = fmaf(xr[3 * F_IN + k], wv, acc3);
    }
    float accs[4] = {acc0, acc1, acc2, acc3};
    #pragma unroll
    for (int j = 0; j < 4; ++j) {
        int row = row0 + j;
        float dv = dinv[row];
        h1[(size_t)row * F_HID + f]   = accs[j];
        agg1[(size_t)row * F_HID + f] = accs[j] * dv * dv;
    }
}

// ---------------- edge scatter (32 features/edge) ----------------
// lane layout: 32 lanes per edge -> coalesced 128B gather of h[src] row,
// 32 contiguous fp32 atomics into agg[dst] row.

__global__ __launch_bounds__(256) void k_scatter32(
        const int* __restrict__ src, const int* __restrict__ dst,
        const float* __restrict__ w, const float* __restrict__ h,
        float* __restrict__ agg) {
    long long gid = (long long)blockIdx.x * blockDim.x + threadIdx.x;
    int e = (int)(gid >> 5);
    int f = (int)(gid & 31);
    if (e < NEDGES) {
        int s = src[e];
        int d = dst[e];
        float val = h[(size_t)s * F_HID + f] * w[e];
        unsafeAtomicAdd(&agg[(size_t)d * F_HID + f], val);
    }
}

// ---------------- post layer-1: h = relu(agg1+b1); h2 = h @ [Wm|Wv]; agg2 init ----

__global__ __launch_bounds__(256) void k_post1(
        const float* __restrict__ agg1, const float* __restrict__ b1,
        const float* __restrict__ Wm, const float* __restrict__ Wv,
        const float* __restrict__ dinv,
        float* __restrict__ h2, float* __restrict__ agg2) {
    __shared__ float Wcat[F_HID * 32];   // [k][j] j<16 -> Wm, j>=16 -> Wv
    __shared__ float hrow[8][F_HID];
    int tx = threadIdx.x;
    for (int idx = tx; idx < F_HID * 32; idx += 256) {
        int k = idx >> 5, j = idx & 31;
        Wcat[idx] = (j < F_OUT) ? Wm[k * F_OUT + j] : Wv[k * F_OUT + (j - F_OUT)];
    }
    int f = tx & 31;
    int lr = tx >> 5;                    // 0..7 local node
    int node = blockIdx.x * 8 + lr;      // grid exact: 12500 * 8 = 100000
    float hv = agg1[(size_t)node * F_HID + f] + b1[f];
    hv = hv > 0.f ? hv : 0.f;
    hrow[lr][f] = hv;
    __syncthreads();
    float acc = 0.f;
    #pragma unroll
    for (int k = 0; k < F_HID; ++k)
        acc = fmaf(hrow[lr][k], Wcat[k * 32 + f], acc);
    float dv = dinv[node];
    h2[(size_t)node * F_HID + f]   = acc;
    agg2[(size_t)node * F_HID + f] = acc * dv * dv;  // self-loop init for layer 2
}

// ---------------- epilogue: split into mu / sigma, add biases ----------------

__global__ void k_out(const float* __restrict__ agg2, const float* __restrict__ bm,
                      const float* __restrict__ bv, float* __restrict__ out) {
    int gid = blockIdx.x * blockDim.x + threadIdx.x;
    if (gid < NNODES * 32) {
        int i = gid >> 5, f = gid & 31;
        float v = agg2[gid];
        if (f < F_OUT) out[(size_t)i * F_OUT + f] = v + bm[f];
        else out[(size_t)NNODES * F_OUT + (size_t)i * F_OUT + (f - F_OUT)] = v + bv[f - F_OUT];
    }
}

// ---------------- launch ----------------

extern "C" void kernel_launch(void* const* d_in, const int* in_sizes, int n_in,
                              void* d_out, int out_size, void* d_ws, size_t ws_size,
                              hipStream_t stream) {
    const float* x   = (const float*)d_in[0];
    const int*   ei  = (const int*)  d_in[1];   // [2][NEDGES]: src then dst
    const float* W1  = (const float*)d_in[2];
    const float* b1  = (const float*)d_in[3];
    const float* Wm  = (const float*)d_in[4];
    const float* bm  = (const float*)d_in[5];
    const float* Wv  = (const float*)d_in[6];
    const float* bv  = (const float*)d_in[7];
    float* out = (float*)d_out;

    const int* src = ei;
    const int* dst = ei + NEDGES;

    // workspace layout (floats). agg2 aliases h1 (h1 dead after scatter1).
    float* ws    = (float*)d_ws;
    float* dinv  = ws;                         // 100000
    float* wE    = ws + 100096;                // 3.2M  (256-aligned offset)
    float* h1    = wE + NEDGES;                // 3.2M
    float* agg1  = h1 + (size_t)NNODES * F_HID;// 3.2M
    float* h2    = agg1 + (size_t)NNODES * F_HID; // 3.2M
    float* agg2  = h1;                         // alias

    // 1) degrees + norm
    k_init_deg<<<(NNODES + 255) / 256, 256, 0, stream>>>(dinv);
    k_count_deg<<<NEDGES / 256, 256, 0, stream>>>(dst, dinv);
    k_dinv<<<(NNODES + 255) / 256, 256, 0, stream>>>(dinv);
    k_edge_w<<<NEDGES / 256, 256, 0, stream>>>(src, dst, dinv, wE);

    // 2) layer 1: GEMM + self-loop init, then edge scatter
    k_gemm1<<<NNODES / 32, 256, 0, stream>>>(x, W1, dinv, h1, agg1);
    k_scatter32<<<(int)(((long long)NEDGES * 32) / 256), 256, 0, stream>>>(
        src, dst, wE, h1, agg1);

    // 3) relu + second transform (mu|sigma fused), layer-2 self-loop init
    k_post1<<<NNODES / 8, 256, 0, stream>>>(agg1, b1, Wm, Wv, dinv, h2, agg2);

    // 4) layer 2 scatter (both heads at once)
    k_scatter32<<<(int)(((long long)NEDGES * 32) / 256), 256, 0, stream>>>(
        src, dst, wE, h2, agg2);

    // 5) epilogue
    k_out<<<(NNODES * 32 + 255) / 256, 256, 0, stream>>>(agg2, bm, bv, out);
}

// Round 2
// 818.419 us; speedup vs baseline: 1.4080x; 1.4080x over previous
//
#include <hip/hip_runtime.h>

#define NNODES 100000
#define NEDGES 3200000
#define F_IN   256
#define F_HID  32
#define F_OUT  16
#define SCAN_BLK 1024
#define NBLK_SCAN ((NNODES + SCAN_BLK - 1) / SCAN_BLK)   // 98

// ---------------- CSR build ----------------

__global__ void k_zero(int* __restrict__ c) {
    int i = blockIdx.x * blockDim.x + threadIdx.x;
    if (i < NNODES) c[i] = 0;
}

__global__ void k_count(const int* __restrict__ dst, int* __restrict__ counts) {
    int e = blockIdx.x * blockDim.x + threadIdx.x;
    if (e < NEDGES) atomicAdd(&counts[dst[e]], 1);
}

template <int NWAVES>
__device__ int block_exscan(int val, int t, int* total) {
    int lane = t & 63, w = t >> 6;
    int v = val;
    #pragma unroll
    for (int d = 1; d < 64; d <<= 1) {
        int tmp = __shfl_up(v, d, 64);
        if (lane >= d) v += tmp;
    }
    __shared__ int wsum[NWAVES];
    if (lane == 63) wsum[w] = v;
    __syncthreads();
    if (w == 0) {
        int s = (lane < NWAVES) ? wsum[lane] : 0;
        #pragma unroll
        for (int d = 1; d < NWAVES; d <<= 1) {
            int tmp = __shfl_up(s, d, 64);
            if (lane >= d) s += tmp;
        }
        if (lane < NWAVES) wsum[lane] = s;
    }
    __syncthreads();
    int incl = v + (w > 0 ? wsum[w - 1] : 0);
    *total = wsum[NWAVES - 1];
    return incl - val;   // exclusive
}

__global__ __launch_bounds__(SCAN_BLK) void k_scan_a(
        const int* __restrict__ counts, int* __restrict__ rowptr, int* __restrict__ bsum) {
    int t = threadIdx.x;
    int gid = blockIdx.x * SCAN_BLK + t;
    int val = (gid < NNODES) ? counts[gid] : 0;
    int total;
    int ex = block_exscan<16>(val, t, &total);
    if (gid < NNODES) rowptr[gid] = ex;
    if (t == 0) bsum[blockIdx.x] = total;
}

__global__ __launch_bounds__(128) void k_scan_b(int* __restrict__ bsum) {
    int t = threadIdx.x;
    int val = (t < NBLK_SCAN) ? bsum[t] : 0;
    int total;
    int ex = block_exscan<2>(val, t, &total);
    if (t < NBLK_SCAN) bsum[t] = ex;
}

// cursor aliases counts: read old count, then overwrite with start offset.
__global__ __launch_bounds__(SCAN_BLK) void k_scan_c(
        const int* __restrict__ bsum, int* __restrict__ rowptr,
        int* __restrict__ cursor, float* __restrict__ dinv) {
    int gid = blockIdx.x * SCAN_BLK + threadIdx.x;
    if (gid < NNODES) {
        int c = cursor[gid];                  // = counts[gid]
        int r = rowptr[gid] + bsum[blockIdx.x];
        rowptr[gid] = r;
        cursor[gid] = r;
        dinv[gid] = rsqrtf((float)c + 1.0f);  // degree + self loop
    }
    if (gid == 0) rowptr[NNODES] = NEDGES;
}

__global__ void k_fill(const int* __restrict__ src, const int* __restrict__ dst,
                       int* __restrict__ cursor, int* __restrict__ csr) {
    int e = blockIdx.x * blockDim.x + threadIdx.x;
    if (e < NEDGES) {
        int pos = atomicAdd(&cursor[dst[e]], 1);
        csr[pos] = src[e];
    }
}

// ---------------- layer-1 GEMM: g1 = (x @ W1) * dinv[row] ----------------

__global__ __launch_bounds__(256) void k_gemm1(
        const float* __restrict__ x, const float* __restrict__ W1,
        const float* __restrict__ dinv, float* __restrict__ g1) {
    __shared__ float ldsW[F_IN * F_HID];
    int tx = threadIdx.x;
    for (int idx = tx; idx < F_IN * F_HID; idx += 256) ldsW[idx] = W1[idx];
    __syncthreads();

    int f = tx & 31;
    int rg = tx >> 5;
    int row0 = blockIdx.x * 32 + rg * 4;
    const float* xr = x + (size_t)row0 * F_IN;

    float acc0 = 0.f, acc1 = 0.f, acc2 = 0.f, acc3 = 0.f;
    #pragma unroll 8
    for (int k = 0; k < F_IN; ++k) {
        float wv = ldsW[k * F_HID + f];
        acc0 = fmaf(xr[k],            wv, acc0);
        acc1 = fmaf(xr[F_IN + k],     wv, acc1);
        acc2 = fmaf(xr[2 * F_IN + k], wv, acc2);
        acc3 = fmaf(xr[3 * F_IN + k], wv, acc3);
    }
    float accs[4] = {acc0, acc1, acc2, acc3};
    #pragma unroll
    for (int j = 0; j < 4; ++j) {
        int row = row0 + j;
        g1[(size_t)row * F_HID + f] = accs[j] * dinv[row];
    }
}

// ---------------- gather: agg[d] = dinv[d] * (g[d] + sum_{e in in(d)} g[src_e]) ----

__global__ __launch_bounds__(256) void k_gather(
        const int* __restrict__ rowptr, const int* __restrict__ csr,
        const float* __restrict__ dinv, const float* __restrict__ g,
        float* __restrict__ agg) {
    int tx = threadIdx.x;
    int f = tx & 31;
    int node = blockIdx.x * 8 + (tx >> 5);
    int start = rowptr[node], end = rowptr[node + 1];
    float acc = g[(size_t)node * F_HID + f];   // self loop
    int j = start;
    for (; j + 4 <= end; j += 4) {
        int s0 = csr[j], s1 = csr[j + 1], s2 = csr[j + 2], s3 = csr[j + 3];
        float a0 = g[(size_t)s0 * F_HID + f];
        float a1 = g[(size_t)s1 * F_HID + f];
        float a2 = g[(size_t)s2 * F_HID + f];
        float a3 = g[(size_t)s3 * F_HID + f];
        acc += (a0 + a1) + (a2 + a3);
    }
    for (; j < end; ++j) acc += g[(size_t)csr[j] * F_HID + f];
    agg[(size_t)node * F_HID + f] = dinv[node] * acc;
}

// ---------------- post layer-1: h = relu(agg1+b1); g2 = (h @ [Wm|Wv]) * dinv ----
// g2 may alias agg1 (row consumed into LDS before overwrite).

__global__ __launch_bounds__(256) void k_post1(
        const float* __restrict__ agg1, const float* __restrict__ b1,
        const float* __restrict__ Wm, const float* __restrict__ Wv,
        const float* __restrict__ dinv, float* __restrict__ g2) {
    __shared__ float Wcat[F_HID * 32];
    __shared__ float hrow[8][F_HID];
    int tx = threadIdx.x;
    for (int idx = tx; idx < F_HID * 32; idx += 256) {
        int k = idx >> 5, j = idx & 31;
        Wcat[idx] = (j < F_OUT) ? Wm[k * F_OUT + j] : Wv[k * F_OUT + (j - F_OUT)];
    }
    int f = tx & 31;
    int lr = tx >> 5;
    int node = blockIdx.x * 8 + lr;
    float hv = agg1[(size_t)node * F_HID + f] + b1[f];
    hv = hv > 0.f ? hv : 0.f;
    hrow[lr][f] = hv;
    __syncthreads();
    float acc = 0.f;
    #pragma unroll
    for (int k = 0; k < F_HID; ++k)
        acc = fmaf(hrow[lr][k], Wcat[k * 32 + f], acc);
    g2[(size_t)node * F_HID + f] = acc * dinv[node];
}

// ---------------- epilogue ----------------

__global__ void k_out(const float* __restrict__ agg2, const float* __restrict__ bm,
                      const float* __restrict__ bv, float* __restrict__ out) {
    int gid = blockIdx.x * blockDim.x + threadIdx.x;
    if (gid < NNODES * 32) {
        int i = gid >> 5, f = gid & 31;
        float v = agg2[gid];
        if (f < F_OUT) out[(size_t)i * F_OUT + f] = v + bm[f];
        else out[(size_t)NNODES * F_OUT + (size_t)i * F_OUT + (f - F_OUT)] = v + bv[f - F_OUT];
    }
}

// ---------------- launch ----------------

extern "C" void kernel_launch(void* const* d_in, const int* in_sizes, int n_in,
                              void* d_out, int out_size, void* d_ws, size_t ws_size,
                              hipStream_t stream) {
    const float* x   = (const float*)d_in[0];
    const int*   ei  = (const int*)  d_in[1];
    const float* W1  = (const float*)d_in[2];
    const float* b1  = (const float*)d_in[3];
    const float* Wm  = (const float*)d_in[4];
    const float* bm  = (const float*)d_in[5];
    const float* Wv  = (const float*)d_in[6];
    const float* bv  = (const float*)d_in[7];
    float* out = (float*)d_out;

    const int* src = ei;
    const int* dst = ei + NEDGES;

    // workspace layout (4B elements), ~39.6 MB total:
    char* ws = (char*)d_ws;
    float* dinv   = (float*)ws;                       ws += 100096 * 4;
    int*   counts = (int*)ws;                         ws += 100096 * 4;   // aliased as cursor
    int*   rowptr = (int*)ws;                         ws += 100352 * 4;   // NNODES+1
    int*   bsum   = (int*)ws;                         ws += 128 * 4;
    int*   csr    = (int*)ws;                         ws += (size_t)NEDGES * 4;
    float* g1     = (float*)ws;                       ws += (size_t)NNODES * F_HID * 4;
    float* agg1   = (float*)ws;
    float* g2   = agg1;   // in-place in k_post1 (safe: row staged in LDS first)
    float* agg2 = g1;     // g1 dead after gather1

    // CSR build
    k_zero <<<(NNODES + 255) / 256, 256, 0, stream>>>(counts);
    k_count<<<NEDGES / 256, 256, 0, stream>>>(dst, counts);
    k_scan_a<<<NBLK_SCAN, SCAN_BLK, 0, stream>>>(counts, rowptr, bsum);
    k_scan_b<<<1, 128, 0, stream>>>(bsum);
    k_scan_c<<<NBLK_SCAN, SCAN_BLK, 0, stream>>>(bsum, rowptr, counts /*cursor*/, dinv);
    k_fill <<<NEDGES / 256, 256, 0, stream>>>(src, dst, counts /*cursor*/, csr);

    // layer 1
    k_gemm1 <<<NNODES / 32, 256, 0, stream>>>(x, W1, dinv, g1);
    k_gather<<<NNODES / 8, 256, 0, stream>>>(rowptr, csr, dinv, g1, agg1);

    // layer 2 (mu|sigma fused, one gather)
    k_post1 <<<NNODES / 8, 256, 0, stream>>>(agg1, b1, Wm, Wv, dinv, g2);
    k_gather<<<NNODES / 8, 256, 0, stream>>>(rowptr, csr, dinv, g2, agg2);

    // epilogue
    k_out<<<(NNODES * 32 + 255) / 256, 256, 0, stream>>>(agg2, bm, bv, out);
}

// Round 3
// 523.606 us; speedup vs baseline: 2.2008x; 1.5630x over previous
//
#include <hip/hip_runtime.h>

#define NNODES 100000
#define NEDGES 3200000
#define F_IN   256
#define F_HID  32
#define F_OUT  16

#define NB   196      // ceil(100000/512) buckets of 512 nodes
#define NPB  512      // nodes per bucket
#define NCHUNK 256    // phase-A blocks
#define CHUNK  12500  // edges per phase-A block (256*12500 = 3.2M exact)

// ---------------- bucketed CSR build ----------------

__global__ void k_init(int* __restrict__ bhist) {
    if (threadIdx.x < NB) bhist[threadIdx.x] = 0;
}

__global__ __launch_bounds__(256) void k_bhist(const int* __restrict__ dst,
                                               int* __restrict__ bhist) {
    __shared__ int lh[NB];
    int t = threadIdx.x;
    for (int i = t; i < NB; i += 256) lh[i] = 0;
    __syncthreads();
    for (int i = blockIdx.x * 256 + t; i < NEDGES; i += gridDim.x * 256)
        atomicAdd(&lh[dst[i] >> 9], 1);
    __syncthreads();
    for (int i = t; i < NB; i += 256)
        if (lh[i]) atomicAdd(&bhist[i], lh[i]);
}

__global__ __launch_bounds__(256) void k_bscan(const int* __restrict__ bhist,
                                               int* __restrict__ bbase,
                                               int* __restrict__ bcur) {
    __shared__ int s[256];
    int t = threadIdx.x;
    int my = (t < NB) ? bhist[t] : 0;
    s[t] = my;
    __syncthreads();
    #pragma unroll
    for (int d = 1; d < 256; d <<= 1) {
        int v = (t >= d) ? s[t - d] : 0;
        __syncthreads();
        s[t] += v;
        __syncthreads();
    }
    if (t < NB) {
        int ex = s[t] - my;
        bbase[t] = ex;
        bcur[t]  = ex;
        if (t == NB - 1) bbase[NB] = s[t];   // = NEDGES
    }
}

// Phase A: partition edges into bucket regions as packed records (src<<9)|dstLocal.
// One contiguous chunk per block; one global atomic per (chunk,bucket) keeps each
// record run single-XCD so L2 write-combines full lines.
__global__ __launch_bounds__(256) void k_phaseA(
        const int* __restrict__ src, const int* __restrict__ dst,
        int* __restrict__ bcur, unsigned int* __restrict__ rec) {
    __shared__ int lh[NB];
    __shared__ int lcur[NB];
    int t = threadIdx.x;
    int e0 = blockIdx.x * CHUNK;
    for (int i = t; i < NB; i += 256) lh[i] = 0;
    __syncthreads();
    for (int i = t; i < CHUNK; i += 256)
        atomicAdd(&lh[dst[e0 + i] >> 9], 1);
    __syncthreads();
    for (int i = t; i < NB; i += 256)
        lcur[i] = lh[i] ? atomicAdd(&bcur[i], lh[i]) : 0;
    __syncthreads();
    for (int i = t; i < CHUNK; i += 256) {
        int s = src[e0 + i], d = dst[e0 + i];
        int b = d >> 9;
        int pos = atomicAdd(&lcur[b], 1);
        rec[pos] = ((unsigned)s << 9) | (unsigned)(d & 511);
    }
}

// Phase B: one block per bucket. Per-node hist -> rowptr + dinv, then place
// src into the bucket's contiguous csr region.
__global__ __launch_bounds__(1024) void k_phaseB(
        const unsigned int* __restrict__ rec, const int* __restrict__ bbase,
        int* __restrict__ rowptr, float* __restrict__ dinv, int* __restrict__ csr) {
    __shared__ int lh[NPB];
    __shared__ int lsc[NPB];
    int t = threadIdx.x, b = blockIdx.x;
    int lo = bbase[b], hi = bbase[b + 1];
    for (int i = t; i < NPB; i += 1024) lh[i] = 0;
    __syncthreads();
    for (int i = lo + t; i < hi; i += 1024)
        atomicAdd(&lh[rec[i] & 511], 1);
    __syncthreads();
    if (t < NPB) lsc[t] = lh[t];
    __syncthreads();
    #pragma unroll
    for (int d = 1; d < NPB; d <<= 1) {
        int v = 0;
        if (t < NPB && t >= d) v = lsc[t - d];
        __syncthreads();
        if (t < NPB) lsc[t] += v;
        __syncthreads();
    }
    if (t < NPB) {
        int node = b * NPB + t;
        if (node < NNODES) {
            int ex = lsc[t] - lh[t];
            rowptr[node] = lo + ex;
            dinv[node] = rsqrtf((float)lh[t] + 1.0f);
        }
    }
    if (b == NB - 1 && t == 0) rowptr[NNODES] = NEDGES;
    __syncthreads();
    if (t < NPB) lsc[t] -= lh[t];   // exclusive -> cursor
    __syncthreads();
    for (int i = lo + t; i < hi; i += 1024) {
        unsigned r = rec[i];
        int dl = r & 511;
        int p = atomicAdd(&lsc[dl], 1);
        csr[lo + p] = (int)(r >> 9);
    }
}

// ---------------- layer-1 GEMM: g1 = (x @ W1) * dinv[row] ----------------

__global__ __launch_bounds__(256) void k_gemm1(
        const float* __restrict__ x, const float* __restrict__ W1,
        const float* __restrict__ dinv, float* __restrict__ g1) {
    __shared__ float ldsW[F_IN * F_HID];
    int tx = threadIdx.x;
    for (int idx = tx; idx < F_IN * F_HID; idx += 256) ldsW[idx] = W1[idx];
    __syncthreads();

    int f = tx & 31;
    int rg = tx >> 5;
    int row0 = blockIdx.x * 32 + rg * 4;
    const float* xr = x + (size_t)row0 * F_IN;

    float acc0 = 0.f, acc1 = 0.f, acc2 = 0.f, acc3 = 0.f;
    #pragma unroll 8
    for (int k = 0; k < F_IN; ++k) {
        float wv = ldsW[k * F_HID + f];
        acc0 = fmaf(xr[k],            wv, acc0);
        acc1 = fmaf(xr[F_IN + k],     wv, acc1);
        acc2 = fmaf(xr[2 * F_IN + k], wv, acc2);
        acc3 = fmaf(xr[3 * F_IN + k], wv, acc3);
    }
    float accs[4] = {acc0, acc1, acc2, acc3};
    #pragma unroll
    for (int j = 0; j < 4; ++j) {
        int row = row0 + j;
        g1[(size_t)row * F_HID + f] = accs[j] * dinv[row];
    }
}

// ---------------- gather: agg[d] = dinv[d] * (g[d] + sum in-neighbors g[s]) ----

__global__ __launch_bounds__(256) void k_gather(
        const int* __restrict__ rowptr, const int* __restrict__ csr,
        const float* __restrict__ dinv, const float* __restrict__ g,
        float* __restrict__ agg) {
    int tx = threadIdx.x;
    int f = tx & 31;
    int node = blockIdx.x * 8 + (tx >> 5);
    int start = rowptr[node], end = rowptr[node + 1];
    float acc = g[(size_t)node * F_HID + f];   // self loop
    int j = start;
    for (; j + 4 <= end; j += 4) {
        int s0 = csr[j], s1 = csr[j + 1], s2 = csr[j + 2], s3 = csr[j + 3];
        float a0 = g[(size_t)s0 * F_HID + f];
        float a1 = g[(size_t)s1 * F_HID + f];
        float a2 = g[(size_t)s2 * F_HID + f];
        float a3 = g[(size_t)s3 * F_HID + f];
        acc += (a0 + a1) + (a2 + a3);
    }
    for (; j < end; ++j) acc += g[(size_t)csr[j] * F_HID + f];
    agg[(size_t)node * F_HID + f] = dinv[node] * acc;
}

// ---------------- post layer-1: h = relu(agg1+b1); g2 = (h @ [Wm|Wv]) * dinv ----

__global__ __launch_bounds__(256) void k_post1(
        const float* __restrict__ agg1, const float* __restrict__ b1,
        const float* __restrict__ Wm, const float* __restrict__ Wv,
        const float* __restrict__ dinv, float* __restrict__ g2) {
    __shared__ float Wcat[F_HID * 32];
    __shared__ float hrow[8][F_HID];
    int tx = threadIdx.x;
    for (int idx = tx; idx < F_HID * 32; idx += 256) {
        int k = idx >> 5, j = idx & 31;
        Wcat[idx] = (j < F_OUT) ? Wm[k * F_OUT + j] : Wv[k * F_OUT + (j - F_OUT)];
    }
    int f = tx & 31;
    int lr = tx >> 5;
    int node = blockIdx.x * 8 + lr;
    float hv = agg1[(size_t)node * F_HID + f] + b1[f];
    hv = hv > 0.f ? hv : 0.f;
    hrow[lr][f] = hv;
    __syncthreads();
    float acc = 0.f;
    #pragma unroll
    for (int k = 0; k < F_HID; ++k)
        acc = fmaf(hrow[lr][k], Wcat[k * 32 + f], acc);
    g2[(size_t)node * F_HID + f] = acc * dinv[node];
}

// ---------------- epilogue ----------------

__global__ void k_out(const float* __restrict__ agg2, const float* __restrict__ bm,
                      const float* __restrict__ bv, float* __restrict__ out) {
    int gid = blockIdx.x * blockDim.x + threadIdx.x;
    if (gid < NNODES * 32) {
        int i = gid >> 5, f = gid & 31;
        float v = agg2[gid];
        if (f < F_OUT) out[(size_t)i * F_OUT + f] = v + bm[f];
        else out[(size_t)NNODES * F_OUT + (size_t)i * F_OUT + (f - F_OUT)] = v + bv[f - F_OUT];
    }
}

// ---------------- launch ----------------

extern "C" void kernel_launch(void* const* d_in, const int* in_sizes, int n_in,
                              void* d_out, int out_size, void* d_ws, size_t ws_size,
                              hipStream_t stream) {
    const float* x   = (const float*)d_in[0];
    const int*   ei  = (const int*)  d_in[1];
    const float* W1  = (const float*)d_in[2];
    const float* b1  = (const float*)d_in[3];
    const float* Wm  = (const float*)d_in[4];
    const float* bm  = (const float*)d_in[5];
    const float* Wv  = (const float*)d_in[6];
    const float* bv  = (const float*)d_in[7];
    float* out = (float*)d_out;

    const int* src = ei;
    const int* dst = ei + NEDGES;

    // workspace (4B units), ~39.5 MB:
    char* ws = (char*)d_ws;
    float*        dinv   = (float*)ws;        ws += 100352 * 4;
    int*          bhist  = (int*)ws;          ws += 256 * 4;
    int*          bbase  = (int*)ws;          ws += 256 * 4;
    int*          bcur   = (int*)ws;          ws += 256 * 4;
    int*          rowptr = (int*)ws;          ws += 100352 * 4;   // NNODES+1
    int*          csr    = (int*)ws;          ws += (size_t)NEDGES * 4;
    unsigned int* rec    = (unsigned int*)ws; ws += (size_t)NEDGES * 4;
    float*        agg1   = (float*)ws;

    float* g1   = (float*)rec;   // rec dead after k_phaseB; gemm1 runs after
    float* g2   = agg1;          // in-place in k_post1 (row staged in LDS first)
    float* agg2 = g1;            // g1 dead after gather1

    // CSR build (bucketed counting sort)
    k_init  <<<1, 256, 0, stream>>>(bhist);
    k_bhist <<<256, 256, 0, stream>>>(dst, bhist);
    k_bscan <<<1, 256, 0, stream>>>(bhist, bbase, bcur);
    k_phaseA<<<NCHUNK, 256, 0, stream>>>(src, dst, bcur, rec);
    k_phaseB<<<NB, 1024, 0, stream>>>(rec, bbase, rowptr, dinv, csr);

    // layer 1
    k_gemm1 <<<NNODES / 32, 256, 0, stream>>>(x, W1, dinv, g1);
    k_gather<<<NNODES / 8, 256, 0, stream>>>(rowptr, csr, dinv, g1, agg1);

    // layer 2 (mu|sigma fused, one gather)
    k_post1 <<<NNODES / 8, 256, 0, stream>>>(agg1, b1, Wm, Wv, dinv, g2);
    k_gather<<<NNODES / 8, 256, 0, stream>>>(rowptr, csr, dinv, g2, agg2);

    // epilogue
    k_out<<<(NNODES * 32 + 255) / 256, 256, 0, stream>>>(agg2, bm, bv, out);
}

// Round 4
// 467.981 us; speedup vs baseline: 2.4623x; 1.1189x over previous
//
#include <hip/hip_runtime.h>

#define NNODES 100000
#define NEDGES 3200000
#define F_IN   256
#define F_HID  32
#define F_OUT  16

#define NB   196      // ceil(100000/512) buckets of 512 nodes
#define NPB  512      // nodes per bucket
#define NCHUNK 256    // phase-A blocks
#define CHUNK  12500  // edges per phase-A block (256*12500 = 3.2M exact)

// gemm1 tiling
#define GR 128        // rows per block
#define GK 64         // k-chunk
#define GRID1 ((NNODES + GR - 1) / GR)   // 782

// ---------------- bucketed CSR build ----------------

__global__ void k_init(int* __restrict__ bhist) {
    if (threadIdx.x < NB) bhist[threadIdx.x] = 0;
}

__global__ __launch_bounds__(256) void k_bhist(const int* __restrict__ dst,
                                               int* __restrict__ bhist) {
    __shared__ int lh[NB];
    int t = threadIdx.x;
    for (int i = t; i < NB; i += 256) lh[i] = 0;
    __syncthreads();
    for (int i = blockIdx.x * 256 + t; i < NEDGES; i += gridDim.x * 256)
        atomicAdd(&lh[dst[i] >> 9], 1);
    __syncthreads();
    for (int i = t; i < NB; i += 256)
        if (lh[i]) atomicAdd(&bhist[i], lh[i]);
}

__global__ __launch_bounds__(256) void k_bscan(const int* __restrict__ bhist,
                                               int* __restrict__ bbase,
                                               int* __restrict__ bcur) {
    __shared__ int s[256];
    int t = threadIdx.x;
    int my = (t < NB) ? bhist[t] : 0;
    s[t] = my;
    __syncthreads();
    #pragma unroll
    for (int d = 1; d < 256; d <<= 1) {
        int v = (t >= d) ? s[t - d] : 0;
        __syncthreads();
        s[t] += v;
        __syncthreads();
    }
    if (t < NB) {
        int ex = s[t] - my;
        bbase[t] = ex;
        bcur[t]  = ex;
        if (t == NB - 1) bbase[NB] = s[t];   // = NEDGES
    }
}

// Phase A: partition edges into bucket regions as packed records (src<<9)|dstLocal.
__global__ __launch_bounds__(256) void k_phaseA(
        const int* __restrict__ src, const int* __restrict__ dst,
        int* __restrict__ bcur, unsigned int* __restrict__ rec) {
    __shared__ int lh[NB];
    __shared__ int lcur[NB];
    int t = threadIdx.x;
    int e0 = blockIdx.x * CHUNK;
    for (int i = t; i < NB; i += 256) lh[i] = 0;
    __syncthreads();
    for (int i = t; i < CHUNK; i += 256)
        atomicAdd(&lh[dst[e0 + i] >> 9], 1);
    __syncthreads();
    for (int i = t; i < NB; i += 256)
        lcur[i] = lh[i] ? atomicAdd(&bcur[i], lh[i]) : 0;
    __syncthreads();
    for (int i = t; i < CHUNK; i += 256) {
        int s = src[e0 + i], d = dst[e0 + i];
        int b = d >> 9;
        int pos = atomicAdd(&lcur[b], 1);
        rec[pos] = ((unsigned)s << 9) | (unsigned)(d & 511);
    }
}

// Phase B: one block per bucket: per-node hist -> rowptr + dinv, then place.
__global__ __launch_bounds__(1024) void k_phaseB(
        const unsigned int* __restrict__ rec, const int* __restrict__ bbase,
        int* __restrict__ rowptr, float* __restrict__ dinv, int* __restrict__ csr) {
    __shared__ int lh[NPB];
    __shared__ int lsc[NPB];
    int t = threadIdx.x, b = blockIdx.x;
    int lo = bbase[b], hi = bbase[b + 1];
    for (int i = t; i < NPB; i += 1024) lh[i] = 0;
    __syncthreads();
    for (int i = lo + t; i < hi; i += 1024)
        atomicAdd(&lh[rec[i] & 511], 1);
    __syncthreads();
    if (t < NPB) lsc[t] = lh[t];
    __syncthreads();
    #pragma unroll
    for (int d = 1; d < NPB; d <<= 1) {
        int v = 0;
        if (t < NPB && t >= d) v = lsc[t - d];
        __syncthreads();
        if (t < NPB) lsc[t] += v;
        __syncthreads();
    }
    if (t < NPB) {
        int node = b * NPB + t;
        if (node < NNODES) {
            int ex = lsc[t] - lh[t];
            rowptr[node] = lo + ex;
            dinv[node] = rsqrtf((float)lh[t] + 1.0f);
        }
    }
    if (b == NB - 1 && t == 0) rowptr[NNODES] = NEDGES;
    __syncthreads();
    if (t < NPB) lsc[t] -= lh[t];   // exclusive -> cursor
    __syncthreads();
    for (int i = lo + t; i < hi; i += 1024) {
        unsigned r = rec[i];
        int dl = r & 511;
        int p = atomicAdd(&lsc[dl], 1);
        csr[lo + p] = (int)(r >> 9);
    }
}

// ---------------- layer-1 GEMM: g1 = (x @ W1) * dinv[row] ----------------
// LDS-tiled: 128 rows/block, K staged in chunks of 64, k-major (stride 129 ->
// conflict-free b128 reads). Thread = 4 rows x 4 features; per k-step
// 2x ds_read_b128 feed 16 FMAs (VALU-bound by design). x fetched once, coalesced.

__global__ __launch_bounds__(256) void k_gemm1(
        const float* __restrict__ x, const float* __restrict__ W1,
        const float* __restrict__ dinv, float* __restrict__ g1) {
    __shared__ float xt[GK][GR + 1];      // [k][r], 33 KB
    __shared__ float Wl[F_IN * F_HID];    // 32 KB, [k][f]
    int t = threadIdx.x;
    for (int i = t; i < (F_IN * F_HID) / 4; i += 256)
        ((float4*)Wl)[i] = ((const float4*)W1)[i];

    int fg = (t & 7) * 4;                 // feature base 0..28
    int rg = (t >> 3) * 4;                // row base 0..124
    int row0 = blockIdx.x * GR;

    float acc[4][4] = {};
    for (int kc = 0; kc < F_IN; kc += GK) {
        __syncthreads();                  // covers W stage (1st iter) + xt reuse
        // stage x chunk: 128 rows x 64 k = 2048 float4, coalesced
        for (int i = t; i < (GR * GK) / 4; i += 256) {
            int r  = i >> 4;              // 16 float4 per row
            int k4 = (i & 15) * 4;
            int grow = row0 + r; if (grow >= NNODES) grow = NNODES - 1;
            float4 v = *(const float4*)&x[(size_t)grow * F_IN + kc + k4];
            xt[k4 + 0][r] = v.x; xt[k4 + 1][r] = v.y;
            xt[k4 + 2][r] = v.z; xt[k4 + 3][r] = v.w;
        }
        __syncthreads();
        #pragma unroll 4
        for (int k = 0; k < GK; ++k) {
            float4 xv = *(const float4*)&xt[k][rg];
            float4 wv = *(const float4*)&Wl[(kc + k) * F_HID + fg];
            acc[0][0] = fmaf(xv.x, wv.x, acc[0][0]);
            acc[0][1] = fmaf(xv.x, wv.y, acc[0][1]);
            acc[0][2] = fmaf(xv.x, wv.z, acc[0][2]);
            acc[0][3] = fmaf(xv.x, wv.w, acc[0][3]);
            acc[1][0] = fmaf(xv.y, wv.x, acc[1][0]);
            acc[1][1] = fmaf(xv.y, wv.y, acc[1][1]);
            acc[1][2] = fmaf(xv.y, wv.z, acc[1][2]);
            acc[1][3] = fmaf(xv.y, wv.w, acc[1][3]);
            acc[2][0] = fmaf(xv.z, wv.x, acc[2][0]);
            acc[2][1] = fmaf(xv.z, wv.y, acc[2][1]);
            acc[2][2] = fmaf(xv.z, wv.z, acc[2][2]);
            acc[2][3] = fmaf(xv.z, wv.w, acc[2][3]);
            acc[3][0] = fmaf(xv.w, wv.x, acc[3][0]);
            acc[3][1] = fmaf(xv.w, wv.y, acc[3][1]);
            acc[3][2] = fmaf(xv.w, wv.z, acc[3][2]);
            acc[3][3] = fmaf(xv.w, wv.w, acc[3][3]);
        }
    }
    #pragma unroll
    for (int j = 0; j < 4; ++j) {
        int row = row0 + rg + j;
        if (row < NNODES) {
            float dv = dinv[row];
            float4 o = { acc[j][0] * dv, acc[j][1] * dv,
                         acc[j][2] * dv, acc[j][3] * dv };
            *(float4*)&g1[(size_t)row * F_HID + fg] = o;
        }
    }
}

// ---------------- gather: agg[d] = dinv[d] * (g[d] + sum in-neighbors g[s]) ----

__global__ __launch_bounds__(256) void k_gather(
        const int* __restrict__ rowptr, const int* __restrict__ csr,
        const float* __restrict__ dinv, const float* __restrict__ g,
        float* __restrict__ agg) {
    int tx = threadIdx.x;
    int f = tx & 31;
    int node = blockIdx.x * 8 + (tx >> 5);
    int start = rowptr[node], end = rowptr[node + 1];
    float acc = g[(size_t)node * F_HID + f];   // self loop
    int j = start;
    for (; j + 4 <= end; j += 4) {
        int s0 = csr[j], s1 = csr[j + 1], s2 = csr[j + 2], s3 = csr[j + 3];
        float a0 = g[(size_t)s0 * F_HID + f];
        float a1 = g[(size_t)s1 * F_HID + f];
        float a2 = g[(size_t)s2 * F_HID + f];
        float a3 = g[(size_t)s3 * F_HID + f];
        acc += (a0 + a1) + (a2 + a3);
    }
    for (; j < end; ++j) acc += g[(size_t)csr[j] * F_HID + f];
    agg[(size_t)node * F_HID + f] = dinv[node] * acc;
}

// ---------------- post layer-1: h = relu(agg1+b1); g2 = (h @ [Wm|Wv]) * dinv ----

__global__ __launch_bounds__(256) void k_post1(
        const float* __restrict__ agg1, const float* __restrict__ b1,
        const float* __restrict__ Wm, const float* __restrict__ Wv,
        const float* __restrict__ dinv, float* __restrict__ g2) {
    __shared__ float Wcat[F_HID * 32];
    __shared__ float hrow[8][F_HID];
    int tx = threadIdx.x;
    for (int idx = tx; idx < F_HID * 32; idx += 256) {
        int k = idx >> 5, j = idx & 31;
        Wcat[idx] = (j < F_OUT) ? Wm[k * F_OUT + j] : Wv[k * F_OUT + (j - F_OUT)];
    }
    int f = tx & 31;
    int lr = tx >> 5;
    int node = blockIdx.x * 8 + lr;
    float hv = agg1[(size_t)node * F_HID + f] + b1[f];
    hv = hv > 0.f ? hv : 0.f;
    hrow[lr][f] = hv;
    __syncthreads();
    float acc = 0.f;
    #pragma unroll
    for (int k = 0; k < F_HID; ++k)
        acc = fmaf(hrow[lr][k], Wcat[k * 32 + f], acc);
    g2[(size_t)node * F_HID + f] = acc * dinv[node];
}

// ---------------- epilogue ----------------

__global__ void k_out(const float* __restrict__ agg2, const float* __restrict__ bm,
                      const float* __restrict__ bv, float* __restrict__ out) {
    int gid = blockIdx.x * blockDim.x + threadIdx.x;
    if (gid < NNODES * 32) {
        int i = gid >> 5, f = gid & 31;
        float v = agg2[gid];
        if (f < F_OUT) out[(size_t)i * F_OUT + f] = v + bm[f];
        else out[(size_t)NNODES * F_OUT + (size_t)i * F_OUT + (f - F_OUT)] = v + bv[f - F_OUT];
    }
}

// ---------------- launch ----------------

extern "C" void kernel_launch(void* const* d_in, const int* in_sizes, int n_in,
                              void* d_out, int out_size, void* d_ws, size_t ws_size,
                              hipStream_t stream) {
    const float* x   = (const float*)d_in[0];
    const int*   ei  = (const int*)  d_in[1];
    const float* W1  = (const float*)d_in[2];
    const float* b1  = (const float*)d_in[3];
    const float* Wm  = (const float*)d_in[4];
    const float* bm  = (const float*)d_in[5];
    const float* Wv  = (const float*)d_in[6];
    const float* bv  = (const float*)d_in[7];
    float* out = (float*)d_out;

    const int* src = ei;
    const int* dst = ei + NEDGES;

    // workspace (4B units), ~39.5 MB:
    char* ws = (char*)d_ws;
    float*        dinv   = (float*)ws;        ws += 100352 * 4;
    int*          bhist  = (int*)ws;          ws += 256 * 4;
    int*          bbase  = (int*)ws;          ws += 256 * 4;
    int*          bcur   = (int*)ws;          ws += 256 * 4;
    int*          rowptr = (int*)ws;          ws += 100352 * 4;   // NNODES+1
    int*          csr    = (int*)ws;          ws += (size_t)NEDGES * 4;
    unsigned int* rec    = (unsigned int*)ws; ws += (size_t)NEDGES * 4;
    float*        agg1   = (float*)ws;

    float* g1   = (float*)rec;   // rec dead after k_phaseB; gemm1 runs after
    float* g2   = agg1;          // in-place in k_post1 (row staged in LDS first)
    float* agg2 = g1;            // g1 dead after gather1

    // CSR build (bucketed counting sort)
    k_init  <<<1, 256, 0, stream>>>(bhist);
    k_bhist <<<256, 256, 0, stream>>>(dst, bhist);
    k_bscan <<<1, 256, 0, stream>>>(bhist, bbase, bcur);
    k_phaseA<<<NCHUNK, 256, 0, stream>>>(src, dst, bcur, rec);
    k_phaseB<<<NB, 1024, 0, stream>>>(rec, bbase, rowptr, dinv, csr);

    // layer 1
    k_gemm1 <<<GRID1, 256, 0, stream>>>(x, W1, dinv, g1);
    k_gather<<<NNODES / 8, 256, 0, stream>>>(rowptr, csr, dinv, g1, agg1);

    // layer 2 (mu|sigma fused, one gather)
    k_post1 <<<NNODES / 8, 256, 0, stream>>>(agg1, b1, Wm, Wv, dinv, g2);
    k_gather<<<NNODES / 8, 256, 0, stream>>>(rowptr, csr, dinv, g2, agg2);

    // epilogue
    k_out<<<(NNODES * 32 + 255) / 256, 256, 0, stream>>>(agg2, bm, bv, out);
}

// Round 5
// 447.107 us; speedup vs baseline: 2.5773x; 1.0467x over previous
//
#include <hip/hip_runtime.h>

#define NNODES 100000
#define NEDGES 3200000
#define F_IN   256
#define F_HID  32
#define F_OUT  16

#define NB   196      // ceil(100000/512) buckets of 512 nodes
#define NPB  512      // nodes per bucket
#define NCHUNK 256    // phase-A blocks
#define CHUNK  12500  // edges per phase-A block (256*12500 = 3.2M exact)

#define GR 128
#define GRID1 ((NNODES + GR - 1) / GR)   // 782

// ---------------- bucketed CSR build ----------------

__global__ void k_init(int* __restrict__ bhist) {
    if (threadIdx.x < NB) bhist[threadIdx.x] = 0;
}

__global__ __launch_bounds__(256) void k_bhist(const int* __restrict__ dst,
                                               int* __restrict__ bhist) {
    __shared__ int lh[NB];
    int t = threadIdx.x;
    for (int i = t; i < NB; i += 256) lh[i] = 0;
    __syncthreads();
    for (int i = blockIdx.x * 256 + t; i < NEDGES; i += gridDim.x * 256)
        atomicAdd(&lh[dst[i] >> 9], 1);
    __syncthreads();
    for (int i = t; i < NB; i += 256)
        if (lh[i]) atomicAdd(&bhist[i], lh[i]);
}

__global__ __launch_bounds__(256) void k_bscan(const int* __restrict__ bhist,
                                               int* __restrict__ bbase,
                                               int* __restrict__ bcur) {
    __shared__ int s[256];
    int t = threadIdx.x;
    int my = (t < NB) ? bhist[t] : 0;
    s[t] = my;
    __syncthreads();
    #pragma unroll
    for (int d = 1; d < 256; d <<= 1) {
        int v = (t >= d) ? s[t - d] : 0;
        __syncthreads();
        s[t] += v;
        __syncthreads();
    }
    if (t < NB) {
        int ex = s[t] - my;
        bbase[t] = ex;
        bcur[t]  = ex;
        if (t == NB - 1) bbase[NB] = s[t];   // = NEDGES
    }
}

// Phase A: partition edges into bucket regions as packed records (src<<9)|dstLocal.
__global__ __launch_bounds__(256) void k_phaseA(
        const int* __restrict__ src, const int* __restrict__ dst,
        int* __restrict__ bcur, unsigned int* __restrict__ rec) {
    __shared__ int lh[NB];
    __shared__ int lcur[NB];
    int t = threadIdx.x;
    int e0 = blockIdx.x * CHUNK;
    for (int i = t; i < NB; i += 256) lh[i] = 0;
    __syncthreads();
    for (int i = t; i < CHUNK; i += 256)
        atomicAdd(&lh[dst[e0 + i] >> 9], 1);
    __syncthreads();
    for (int i = t; i < NB; i += 256)
        lcur[i] = lh[i] ? atomicAdd(&bcur[i], lh[i]) : 0;
    __syncthreads();
    for (int i = t; i < CHUNK; i += 256) {
        int s = src[e0 + i], d = dst[e0 + i];
        int b = d >> 9;
        int pos = atomicAdd(&lcur[b], 1);
        rec[pos] = ((unsigned)s << 9) | (unsigned)(d & 511);
    }
}

// Phase B: one block per bucket: per-node hist -> rowptr + dinv, then place.
__global__ __launch_bounds__(1024) void k_phaseB(
        const unsigned int* __restrict__ rec, const int* __restrict__ bbase,
        int* __restrict__ rowptr, float* __restrict__ dinv, int* __restrict__ csr) {
    __shared__ int lh[NPB];
    __shared__ int lsc[NPB];
    int t = threadIdx.x, b = blockIdx.x;
    int lo = bbase[b], hi = bbase[b + 1];
    for (int i = t; i < NPB; i += 1024) lh[i] = 0;
    __syncthreads();
    for (int i = lo + t; i < hi; i += 1024)
        atomicAdd(&lh[rec[i] & 511], 1);
    __syncthreads();
    if (t < NPB) lsc[t] = lh[t];
    __syncthreads();
    #pragma unroll
    for (int d = 1; d < NPB; d <<= 1) {
        int v = 0;
        if (t < NPB && t >= d) v = lsc[t - d];
        __syncthreads();
        if (t < NPB) lsc[t] += v;
        __syncthreads();
    }
    if (t < NPB) {
        int node = b * NPB + t;
        if (node < NNODES) {
            int ex = lsc[t] - lh[t];
            rowptr[node] = lo + ex;
            dinv[node] = rsqrtf((float)lh[t] + 1.0f);
        }
    }
    if (b == NB - 1 && t == 0) rowptr[NNODES] = NEDGES;
    __syncthreads();
    if (t < NPB) lsc[t] -= lh[t];   // exclusive -> cursor
    __syncthreads();
    for (int i = lo + t; i < hi; i += 1024) {
        unsigned r = rec[i];
        int dl = r & 511;
        int p = atomicAdd(&lsc[dl], 1);
        csr[lo + p] = (int)(r >> 9);
    }
}

// ---------------- layer-1 GEMM: g1 = (x @ W1) * dinv[row] ----------------
// Only W1 in LDS (32 KB, one barrier). Thread = 4 rows x 4 features, x read
// directly from global as float4 (8 distinct addrs/wave, broadcast-coalesced,
// lines fully consumed across k). No barriers in the k-loop -> latency hidden
// by ~20 waves/CU of free-running ILP.

__global__ __launch_bounds__(256) void k_gemm1(
        const float* __restrict__ x, const float* __restrict__ W1,
        const float* __restrict__ dinv, float* __restrict__ g1) {
    __shared__ float Wl[F_IN * F_HID];    // [k][f], 32 KB
    int t = threadIdx.x;
    for (int i = t; i < (F_IN * F_HID) / 4; i += 256)
        ((float4*)Wl)[i] = ((const float4*)W1)[i];
    __syncthreads();

    int fg = (t & 7) * 4;
    int rg = (t >> 3) * 4;
    int row0 = blockIdx.x * GR + rg;

    const float* xr0 = x + (size_t)min(row0 + 0, NNODES - 1) * F_IN;
    const float* xr1 = x + (size_t)min(row0 + 1, NNODES - 1) * F_IN;
    const float* xr2 = x + (size_t)min(row0 + 2, NNODES - 1) * F_IN;
    const float* xr3 = x + (size_t)min(row0 + 3, NNODES - 1) * F_IN;

    float acc[4][4] = {};
    #pragma unroll 2
    for (int k = 0; k < F_IN; k += 4) {
        float4 xv0 = *(const float4*)&xr0[k];
        float4 xv1 = *(const float4*)&xr1[k];
        float4 xv2 = *(const float4*)&xr2[k];
        float4 xv3 = *(const float4*)&xr3[k];
        #pragma unroll
        for (int kk = 0; kk < 4; ++kk) {
            float4 wv = *(const float4*)&Wl[(k + kk) * F_HID + fg];
            float xs0 = (&xv0.x)[kk], xs1 = (&xv1.x)[kk];
            float xs2 = (&xv2.x)[kk], xs3 = (&xv3.x)[kk];
            acc[0][0] = fmaf(xs0, wv.x, acc[0][0]);
            acc[0][1] = fmaf(xs0, wv.y, acc[0][1]);
            acc[0][2] = fmaf(xs0, wv.z, acc[0][2]);
            acc[0][3] = fmaf(xs0, wv.w, acc[0][3]);
            acc[1][0] = fmaf(xs1, wv.x, acc[1][0]);
            acc[1][1] = fmaf(xs1, wv.y, acc[1][1]);
            acc[1][2] = fmaf(xs1, wv.z, acc[1][2]);
            acc[1][3] = fmaf(xs1, wv.w, acc[1][3]);
            acc[2][0] = fmaf(xs2, wv.x, acc[2][0]);
            acc[2][1] = fmaf(xs2, wv.y, acc[2][1]);
            acc[2][2] = fmaf(xs2, wv.z, acc[2][2]);
            acc[2][3] = fmaf(xs2, wv.w, acc[2][3]);
            acc[3][0] = fmaf(xs3, wv.x, acc[3][0]);
            acc[3][1] = fmaf(xs3, wv.y, acc[3][1]);
            acc[3][2] = fmaf(xs3, wv.z, acc[3][2]);
            acc[3][3] = fmaf(xs3, wv.w, acc[3][3]);
        }
    }
    #pragma unroll
    for (int j = 0; j < 4; ++j) {
        int row = row0 + j;
        if (row < NNODES) {
            float dv = dinv[row];
            float4 o = { acc[j][0] * dv, acc[j][1] * dv,
                         acc[j][2] * dv, acc[j][3] * dv };
            *(float4*)&g1[(size_t)row * F_HID + fg] = o;
        }
    }
}

// ---------------- gather layer 1 (fused relu + [Wm|Wv] transform) ----------------
// agg = dinv[d]*(g1[d] + sum g1[src]); h = relu(agg + b1); g2 = (h @ Wcat)*dinv[d].

__global__ __launch_bounds__(256) void k_gather_l1(
        const int* __restrict__ rowptr, const int* __restrict__ csr,
        const float* __restrict__ dinv, const float* __restrict__ g,
        const float* __restrict__ b1, const float* __restrict__ Wm,
        const float* __restrict__ Wv, float* __restrict__ g2) {
    __shared__ float Wcat[F_HID * 32];
    __shared__ float hrow[8][F_HID + 1];
    int tx = threadIdx.x;
    for (int idx = tx; idx < F_HID * 32; idx += 256) {
        int k = idx >> 5, j = idx & 31;
        Wcat[idx] = (j < F_OUT) ? Wm[k * F_OUT + j] : Wv[k * F_OUT + (j - F_OUT)];
    }
    int f = tx & 31;
    int lr = tx >> 5;
    int node = blockIdx.x * 8 + lr;
    int start = rowptr[node], end = rowptr[node + 1];
    float acc = g[(size_t)node * F_HID + f];   // self loop
    int j = start;
    for (; j + 4 <= end; j += 4) {
        int s0 = csr[j], s1 = csr[j + 1], s2 = csr[j + 2], s3 = csr[j + 3];
        float a0 = g[(size_t)s0 * F_HID + f];
        float a1 = g[(size_t)s1 * F_HID + f];
        float a2 = g[(size_t)s2 * F_HID + f];
        float a3 = g[(size_t)s3 * F_HID + f];
        acc += (a0 + a1) + (a2 + a3);
    }
    for (; j < end; ++j) acc += g[(size_t)csr[j] * F_HID + f];
    float dv = dinv[node];
    float hv = dv * acc + b1[f];
    hrow[lr][f] = hv > 0.f ? hv : 0.f;
    __syncthreads();
    float o = 0.f;
    #pragma unroll
    for (int k = 0; k < F_HID; ++k)
        o = fmaf(hrow[lr][k], Wcat[k * 32 + f], o);
    g2[(size_t)node * F_HID + f] = o * dv;
}

// ---------------- gather layer 2 (fused bias + mu/sigma split to out) ----------

__global__ __launch_bounds__(256) void k_gather_out(
        const int* __restrict__ rowptr, const int* __restrict__ csr,
        const float* __restrict__ dinv, const float* __restrict__ g,
        const float* __restrict__ bm, const float* __restrict__ bv,
        float* __restrict__ out) {
    int tx = threadIdx.x;
    int f = tx & 31;
    int node = blockIdx.x * 8 + (tx >> 5);
    int start = rowptr[node], end = rowptr[node + 1];
    float acc = g[(size_t)node * F_HID + f];   // self loop
    int j = start;
    for (; j + 4 <= end; j += 4) {
        int s0 = csr[j], s1 = csr[j + 1], s2 = csr[j + 2], s3 = csr[j + 3];
        float a0 = g[(size_t)s0 * F_HID + f];
        float a1 = g[(size_t)s1 * F_HID + f];
        float a2 = g[(size_t)s2 * F_HID + f];
        float a3 = g[(size_t)s3 * F_HID + f];
        acc += (a0 + a1) + (a2 + a3);
    }
    for (; j < end; ++j) acc += g[(size_t)csr[j] * F_HID + f];
    float v = dinv[node] * acc;
    if (f < F_OUT) out[(size_t)node * F_OUT + f] = v + bm[f];
    else out[(size_t)NNODES * F_OUT + (size_t)node * F_OUT + (f - F_OUT)] = v + bv[f - F_OUT];
}

// ---------------- launch ----------------

extern "C" void kernel_launch(void* const* d_in, const int* in_sizes, int n_in,
                              void* d_out, int out_size, void* d_ws, size_t ws_size,
                              hipStream_t stream) {
    const float* x   = (const float*)d_in[0];
    const int*   ei  = (const int*)  d_in[1];
    const float* W1  = (const float*)d_in[2];
    const float* b1  = (const float*)d_in[3];
    const float* Wm  = (const float*)d_in[4];
    const float* bm  = (const float*)d_in[5];
    const float* Wv  = (const float*)d_in[6];
    const float* bv  = (const float*)d_in[7];
    float* out = (float*)d_out;

    const int* src = ei;
    const int* dst = ei + NEDGES;

    // workspace (4B units):
    char* ws = (char*)d_ws;
    float*        dinv   = (float*)ws;        ws += 100352 * 4;
    int*          bhist  = (int*)ws;          ws += 256 * 4;
    int*          bbase  = (int*)ws;          ws += 256 * 4;
    int*          bcur   = (int*)ws;          ws += 256 * 4;
    int*          rowptr = (int*)ws;          ws += 100352 * 4;   // NNODES+1
    int*          csr    = (int*)ws;          ws += (size_t)NEDGES * 4;
    unsigned int* rec    = (unsigned int*)ws; ws += (size_t)NEDGES * 4;
    float*        g2     = (float*)ws;

    float* g1 = (float*)rec;   // rec dead after k_phaseB; gemm1 runs after

    // CSR build (bucketed counting sort)
    k_init  <<<1, 256, 0, stream>>>(bhist);
    k_bhist <<<256, 256, 0, stream>>>(dst, bhist);
    k_bscan <<<1, 256, 0, stream>>>(bhist, bbase, bcur);
    k_phaseA<<<NCHUNK, 256, 0, stream>>>(src, dst, bcur, rec);
    k_phaseB<<<NB, 1024, 0, stream>>>(rec, bbase, rowptr, dinv, csr);

    // layer 1 GEMM
    k_gemm1<<<GRID1, 256, 0, stream>>>(x, W1, dinv, g1);

    // gather 1 + relu + second transform (mu|sigma fused)
    k_gather_l1<<<NNODES / 8, 256, 0, stream>>>(rowptr, csr, dinv, g1, b1, Wm, Wv, g2);

    // gather 2 + bias + split to out
    k_gather_out<<<NNODES / 8, 256, 0, stream>>>(rowptr, csr, dinv, g2, bm, bv, out);
}

// Round 6
// 403.498 us; speedup vs baseline: 2.8558x; 1.1081x over previous
//
#include <hip/hip_runtime.h>
#include <hip/hip_fp16.h>

#define NNODES 100000
#define NEDGES 3200000
#define F_IN   256
#define F_HID  32
#define F_OUT  16

#define NB   196      // ceil(100000/512) buckets of 512 nodes
#define NPB  512      // nodes per bucket
#define NCHUNK 256    // phase-A blocks
#define CHUNK  12500  // edges per phase-A block (256*12500 = 3.2M exact)

#define GR 128
#define GRID1 ((NNODES + GR - 1) / GR)   // 782

// ---------------- bucketed CSR build ----------------

__global__ void k_init(int* __restrict__ bhist) {
    if (threadIdx.x < NB) bhist[threadIdx.x] = 0;
}

__global__ __launch_bounds__(256) void k_bhist(const int* __restrict__ dst,
                                               int* __restrict__ bhist) {
    __shared__ int lh[NB];
    int t = threadIdx.x;
    for (int i = t; i < NB; i += 256) lh[i] = 0;
    __syncthreads();
    for (int i = blockIdx.x * 256 + t; i < NEDGES; i += gridDim.x * 256)
        atomicAdd(&lh[dst[i] >> 9], 1);
    __syncthreads();
    for (int i = t; i < NB; i += 256)
        if (lh[i]) atomicAdd(&bhist[i], lh[i]);
}

__global__ __launch_bounds__(256) void k_bscan(const int* __restrict__ bhist,
                                               int* __restrict__ bbase,
                                               int* __restrict__ bcur) {
    __shared__ int s[256];
    int t = threadIdx.x;
    int my = (t < NB) ? bhist[t] : 0;
    s[t] = my;
    __syncthreads();
    #pragma unroll
    for (int d = 1; d < 256; d <<= 1) {
        int v = (t >= d) ? s[t - d] : 0;
        __syncthreads();
        s[t] += v;
        __syncthreads();
    }
    if (t < NB) {
        int ex = s[t] - my;
        bbase[t] = ex;
        bcur[t]  = ex;
        if (t == NB - 1) bbase[NB] = s[t];   // = NEDGES
    }
}

// Phase A: partition edges into bucket regions as packed records (src<<9)|dstLocal.
__global__ __launch_bounds__(256) void k_phaseA(
        const int* __restrict__ src, const int* __restrict__ dst,
        int* __restrict__ bcur, unsigned int* __restrict__ rec) {
    __shared__ int lh[NB];
    __shared__ int lcur[NB];
    int t = threadIdx.x;
    int e0 = blockIdx.x * CHUNK;
    for (int i = t; i < NB; i += 256) lh[i] = 0;
    __syncthreads();
    for (int i = t; i < CHUNK; i += 256)
        atomicAdd(&lh[dst[e0 + i] >> 9], 1);
    __syncthreads();
    for (int i = t; i < NB; i += 256)
        lcur[i] = lh[i] ? atomicAdd(&bcur[i], lh[i]) : 0;
    __syncthreads();
    for (int i = t; i < CHUNK; i += 256) {
        int s = src[e0 + i], d = dst[e0 + i];
        int b = d >> 9;
        int pos = atomicAdd(&lcur[b], 1);
        rec[pos] = ((unsigned)s << 9) | (unsigned)(d & 511);
    }
}

// Phase B: one block per bucket: per-node hist -> rowptr + dinv, then place.
__global__ __launch_bounds__(1024) void k_phaseB(
        const unsigned int* __restrict__ rec, const int* __restrict__ bbase,
        int* __restrict__ rowptr, float* __restrict__ dinv, int* __restrict__ csr) {
    __shared__ int lh[NPB];
    __shared__ int lsc[NPB];
    int t = threadIdx.x, b = blockIdx.x;
    int lo = bbase[b], hi = bbase[b + 1];
    for (int i = t; i < NPB; i += 1024) lh[i] = 0;
    __syncthreads();
    for (int i = lo + t; i < hi; i += 1024)
        atomicAdd(&lh[rec[i] & 511], 1);
    __syncthreads();
    if (t < NPB) lsc[t] = lh[t];
    __syncthreads();
    #pragma unroll
    for (int d = 1; d < NPB; d <<= 1) {
        int v = 0;
        if (t < NPB && t >= d) v = lsc[t - d];
        __syncthreads();
        if (t < NPB) lsc[t] += v;
        __syncthreads();
    }
    if (t < NPB) {
        int node = b * NPB + t;
        if (node < NNODES) {
            int ex = lsc[t] - lh[t];
            rowptr[node] = lo + ex;
            dinv[node] = rsqrtf((float)lh[t] + 1.0f);
        }
    }
    if (b == NB - 1 && t == 0) rowptr[NNODES] = NEDGES;
    __syncthreads();
    if (t < NPB) lsc[t] -= lh[t];   // exclusive -> cursor
    __syncthreads();
    for (int i = lo + t; i < hi; i += 1024) {
        unsigned r = rec[i];
        int dl = r & 511;
        int p = atomicAdd(&lsc[dl], 1);
        csr[lo + p] = (int)(r >> 9);
    }
}

// ---------------- layer-1 GEMM: g1 = fp16((x @ W1) * dinv[row]) ----------------

__global__ __launch_bounds__(256) void k_gemm1(
        const float* __restrict__ x, const float* __restrict__ W1,
        const float* __restrict__ dinv, __half2* __restrict__ g1) {
    __shared__ float Wl[F_IN * F_HID];    // [k][f], 32 KB
    int t = threadIdx.x;
    for (int i = t; i < (F_IN * F_HID) / 4; i += 256)
        ((float4*)Wl)[i] = ((const float4*)W1)[i];
    __syncthreads();

    int fg = (t & 7) * 4;
    int rg = (t >> 3) * 4;
    int row0 = blockIdx.x * GR + rg;

    const float* xr0 = x + (size_t)min(row0 + 0, NNODES - 1) * F_IN;
    const float* xr1 = x + (size_t)min(row0 + 1, NNODES - 1) * F_IN;
    const float* xr2 = x + (size_t)min(row0 + 2, NNODES - 1) * F_IN;
    const float* xr3 = x + (size_t)min(row0 + 3, NNODES - 1) * F_IN;

    float acc[4][4] = {};
    #pragma unroll 2
    for (int k = 0; k < F_IN; k += 4) {
        float4 xv0 = *(const float4*)&xr0[k];
        float4 xv1 = *(const float4*)&xr1[k];
        float4 xv2 = *(const float4*)&xr2[k];
        float4 xv3 = *(const float4*)&xr3[k];
        #pragma unroll
        for (int kk = 0; kk < 4; ++kk) {
            float4 wv = *(const float4*)&Wl[(k + kk) * F_HID + fg];
            float xs0 = (&xv0.x)[kk], xs1 = (&xv1.x)[kk];
            float xs2 = (&xv2.x)[kk], xs3 = (&xv3.x)[kk];
            acc[0][0] = fmaf(xs0, wv.x, acc[0][0]);
            acc[0][1] = fmaf(xs0, wv.y, acc[0][1]);
            acc[0][2] = fmaf(xs0, wv.z, acc[0][2]);
            acc[0][3] = fmaf(xs0, wv.w, acc[0][3]);
            acc[1][0] = fmaf(xs1, wv.x, acc[1][0]);
            acc[1][1] = fmaf(xs1, wv.y, acc[1][1]);
            acc[1][2] = fmaf(xs1, wv.z, acc[1][2]);
            acc[1][3] = fmaf(xs1, wv.w, acc[1][3]);
            acc[2][0] = fmaf(xs2, wv.x, acc[2][0]);
            acc[2][1] = fmaf(xs2, wv.y, acc[2][1]);
            acc[2][2] = fmaf(xs2, wv.z, acc[2][2]);
            acc[2][3] = fmaf(xs2, wv.w, acc[2][3]);
            acc[3][0] = fmaf(xs3, wv.x, acc[3][0]);
            acc[3][1] = fmaf(xs3, wv.y, acc[3][1]);
            acc[3][2] = fmaf(xs3, wv.z, acc[3][2]);
            acc[3][3] = fmaf(xs3, wv.w, acc[3][3]);
        }
    }
    #pragma unroll
    for (int j = 0; j < 4; ++j) {
        int row = row0 + j;
        if (row < NNODES) {
            float dv = dinv[row];
            __half2 ha = __floats2half2_rn(acc[j][0] * dv, acc[j][1] * dv);
            __half2 hb = __floats2half2_rn(acc[j][2] * dv, acc[j][3] * dv);
            g1[(size_t)row * 16 + (fg >> 1)]     = ha;
            g1[(size_t)row * 16 + (fg >> 1) + 1] = hb;
        }
    }
}

// ---------------- gather layer 1 (fp16 rows; fused relu + [Wm|Wv]) ----------------
// 16 lanes/node, each lane owns 2 features via __half2; fp32 accumulation.

__global__ __launch_bounds__(256) void k_gather_l1(
        const int* __restrict__ rowptr, const int* __restrict__ csr,
        const float* __restrict__ dinv, const __half2* __restrict__ g,
        const float* __restrict__ b1, const float* __restrict__ Wm,
        const float* __restrict__ Wv, __half2* __restrict__ g2) {
    __shared__ float Wcat[F_HID * 32];
    __shared__ float hrow[16][F_HID + 2];
    int tx = threadIdx.x;
    for (int idx = tx; idx < F_HID * 32; idx += 256) {
        int k = idx >> 5, j = idx & 31;
        Wcat[idx] = (j < F_OUT) ? Wm[k * F_OUT + j] : Wv[k * F_OUT + (j - F_OUT)];
    }
    int f2 = tx & 15;                    // feature pair
    int lr = tx >> 4;                    // 0..15 local node
    int node = blockIdx.x * 16 + lr;
    int start = rowptr[node], end = rowptr[node + 1];
    float2 acc = __half22float2(g[(size_t)node * 16 + f2]);   // self loop
    int j = start;
    for (; j + 4 <= end; j += 4) {
        int s0 = csr[j], s1 = csr[j + 1], s2 = csr[j + 2], s3 = csr[j + 3];
        float2 a0 = __half22float2(g[(size_t)s0 * 16 + f2]);
        float2 a1 = __half22float2(g[(size_t)s1 * 16 + f2]);
        float2 a2 = __half22float2(g[(size_t)s2 * 16 + f2]);
        float2 a3 = __half22float2(g[(size_t)s3 * 16 + f2]);
        acc.x += (a0.x + a1.x) + (a2.x + a3.x);
        acc.y += (a0.y + a1.y) + (a2.y + a3.y);
    }
    for (; j < end; ++j) {
        float2 a = __half22float2(g[(size_t)csr[j] * 16 + f2]);
        acc.x += a.x; acc.y += a.y;
    }
    float dv = dinv[node];
    float h0 = dv * acc.x + b1[2 * f2];
    float h1 = dv * acc.y + b1[2 * f2 + 1];
    hrow[lr][2 * f2]     = h0 > 0.f ? h0 : 0.f;
    hrow[lr][2 * f2 + 1] = h1 > 0.f ? h1 : 0.f;
    __syncthreads();
    float o0 = 0.f, o1 = 0.f;
    #pragma unroll
    for (int k = 0; k < F_HID; ++k) {
        float hv = hrow[lr][k];
        o0 = fmaf(hv, Wcat[k * 32 + 2 * f2], o0);
        o1 = fmaf(hv, Wcat[k * 32 + 2 * f2 + 1], o1);
    }
    g2[(size_t)node * 16 + f2] = __floats2half2_rn(o0 * dv, o1 * dv);
}

// ---------------- gather layer 2 (fp16 rows; fused bias + mu/sigma split) --------

__global__ __launch_bounds__(256) void k_gather_out(
        const int* __restrict__ rowptr, const int* __restrict__ csr,
        const float* __restrict__ dinv, const __half2* __restrict__ g,
        const float* __restrict__ bm, const float* __restrict__ bv,
        float* __restrict__ out) {
    int tx = threadIdx.x;
    int f2 = tx & 15;
    int node = blockIdx.x * 16 + (tx >> 4);
    int start = rowptr[node], end = rowptr[node + 1];
    float2 acc = __half22float2(g[(size_t)node * 16 + f2]);   // self loop
    int j = start;
    for (; j + 4 <= end; j += 4) {
        int s0 = csr[j], s1 = csr[j + 1], s2 = csr[j + 2], s3 = csr[j + 3];
        float2 a0 = __half22float2(g[(size_t)s0 * 16 + f2]);
        float2 a1 = __half22float2(g[(size_t)s1 * 16 + f2]);
        float2 a2 = __half22float2(g[(size_t)s2 * 16 + f2]);
        float2 a3 = __half22float2(g[(size_t)s3 * 16 + f2]);
        acc.x += (a0.x + a1.x) + (a2.x + a3.x);
        acc.y += (a0.y + a1.y) + (a2.y + a3.y);
    }
    for (; j < end; ++j) {
        float2 a = __half22float2(g[(size_t)csr[j] * 16 + f2]);
        acc.x += a.x; acc.y += a.y;
    }
    float dv = dinv[node];
    int f = 2 * f2;
    if (f < F_OUT) {
        float2 o = { dv * acc.x + bm[f], dv * acc.y + bm[f + 1] };
        *(float2*)&out[(size_t)node * F_OUT + f] = o;
    } else {
        float2 o = { dv * acc.x + bv[f - F_OUT], dv * acc.y + bv[f - F_OUT + 1] };
        *(float2*)&out[(size_t)NNODES * F_OUT + (size_t)node * F_OUT + (f - F_OUT)] = o;
    }
}

// ---------------- launch ----------------

extern "C" void kernel_launch(void* const* d_in, const int* in_sizes, int n_in,
                              void* d_out, int out_size, void* d_ws, size_t ws_size,
                              hipStream_t stream) {
    const float* x   = (const float*)d_in[0];
    const int*   ei  = (const int*)  d_in[1];
    const float* W1  = (const float*)d_in[2];
    const float* b1  = (const float*)d_in[3];
    const float* Wm  = (const float*)d_in[4];
    const float* bm  = (const float*)d_in[5];
    const float* Wv  = (const float*)d_in[6];
    const float* bv  = (const float*)d_in[7];
    float* out = (float*)d_out;

    const int* src = ei;
    const int* dst = ei + NEDGES;

    // workspace (4B units):
    char* ws = (char*)d_ws;
    float*        dinv   = (float*)ws;        ws += 100352 * 4;
    int*          bhist  = (int*)ws;          ws += 256 * 4;
    int*          bbase  = (int*)ws;          ws += 256 * 4;
    int*          bcur   = (int*)ws;          ws += 256 * 4;
    int*          rowptr = (int*)ws;          ws += 100352 * 4;   // NNODES+1
    int*          csr    = (int*)ws;          ws += (size_t)NEDGES * 4;
    unsigned int* rec    = (unsigned int*)ws; ws += (size_t)NEDGES * 4;
    __half2*      g2     = (__half2*)ws;

    __half2* g1 = (__half2*)rec;   // rec dead after k_phaseB; gemm1 runs after

    // CSR build (bucketed counting sort)
    k_init  <<<1, 256, 0, stream>>>(bhist);
    k_bhist <<<256, 256, 0, stream>>>(dst, bhist);
    k_bscan <<<1, 256, 0, stream>>>(bhist, bbase, bcur);
    k_phaseA<<<NCHUNK, 256, 0, stream>>>(src, dst, bcur, rec);
    k_phaseB<<<NB, 1024, 0, stream>>>(rec, bbase, rowptr, dinv, csr);

    // layer 1 GEMM
    k_gemm1<<<GRID1, 256, 0, stream>>>(x, W1, dinv, g1);

    // gather 1 + relu + second transform (mu|sigma fused)
    k_gather_l1<<<NNODES / 16, 256, 0, stream>>>(rowptr, csr, dinv, g1, b1, Wm, Wv, g2);

    // gather 2 + bias + split to out
    k_gather_out<<<NNODES / 16, 256, 0, stream>>>(rowptr, csr, dinv, g2, bm, bv, out);
}

// Round 7
// 394.103 us; speedup vs baseline: 2.9239x; 1.0238x over previous
//
#include <hip/hip_runtime.h>
#include <hip/hip_fp16.h>

#define NNODES 100000
#define NEDGES 3200000
#define F_IN   256
#define F_HID  32
#define F_OUT  16

#define NB   196      // ceil(100000/512) buckets of 512 nodes
#define NPB  512      // nodes per bucket
#define NCHUNK 256    // phase-A blocks
#define CHUNK  12500  // edges per phase-A block (256*12500 = 3.2M exact)

#define GR 64
#define GRID1 ((NNODES + GR - 1) / GR)   // 1563

// ---------------- bucketed CSR build ----------------

__global__ void k_init(int* __restrict__ bhist) {
    if (threadIdx.x < NB) bhist[threadIdx.x] = 0;
}

__global__ __launch_bounds__(256) void k_bhist(const int* __restrict__ dst,
                                               int* __restrict__ bhist) {
    __shared__ int lh[NB];
    int t = threadIdx.x;
    for (int i = t; i < NB; i += 256) lh[i] = 0;
    __syncthreads();
    for (int i = blockIdx.x * 256 + t; i < NEDGES; i += gridDim.x * 256)
        atomicAdd(&lh[dst[i] >> 9], 1);
    __syncthreads();
    for (int i = t; i < NB; i += 256)
        if (lh[i]) atomicAdd(&bhist[i], lh[i]);
}

__global__ __launch_bounds__(256) void k_bscan(const int* __restrict__ bhist,
                                               int* __restrict__ bbase,
                                               int* __restrict__ bcur) {
    __shared__ int s[256];
    int t = threadIdx.x;
    int my = (t < NB) ? bhist[t] : 0;
    s[t] = my;
    __syncthreads();
    #pragma unroll
    for (int d = 1; d < 256; d <<= 1) {
        int v = (t >= d) ? s[t - d] : 0;
        __syncthreads();
        s[t] += v;
        __syncthreads();
    }
    if (t < NB) {
        int ex = s[t] - my;
        bbase[t] = ex;
        bcur[t]  = ex;
        if (t == NB - 1) bbase[NB] = s[t];   // = NEDGES
    }
}

// Phase A: partition edges into bucket regions as packed records (src<<9)|dstLocal.
__global__ __launch_bounds__(256) void k_phaseA(
        const int* __restrict__ src, const int* __restrict__ dst,
        int* __restrict__ bcur, unsigned int* __restrict__ rec) {
    __shared__ int lh[NB];
    __shared__ int lcur[NB];
    int t = threadIdx.x;
    int e0 = blockIdx.x * CHUNK;
    for (int i = t; i < NB; i += 256) lh[i] = 0;
    __syncthreads();
    for (int i = t; i < CHUNK; i += 256)
        atomicAdd(&lh[dst[e0 + i] >> 9], 1);
    __syncthreads();
    for (int i = t; i < NB; i += 256)
        lcur[i] = lh[i] ? atomicAdd(&bcur[i], lh[i]) : 0;
    __syncthreads();
    for (int i = t; i < CHUNK; i += 256) {
        int s = src[e0 + i], d = dst[e0 + i];
        int b = d >> 9;
        int pos = atomicAdd(&lcur[b], 1);
        rec[pos] = ((unsigned)s << 9) | (unsigned)(d & 511);
    }
}

// Phase B: one block per bucket: per-node hist -> rowptr + dinv, then place.
__global__ __launch_bounds__(1024) void k_phaseB(
        const unsigned int* __restrict__ rec, const int* __restrict__ bbase,
        int* __restrict__ rowptr, float* __restrict__ dinv, int* __restrict__ csr) {
    __shared__ int lh[NPB];
    __shared__ int lsc[NPB];
    int t = threadIdx.x, b = blockIdx.x;
    int lo = bbase[b], hi = bbase[b + 1];
    for (int i = t; i < NPB; i += 1024) lh[i] = 0;
    __syncthreads();
    for (int i = lo + t; i < hi; i += 1024)
        atomicAdd(&lh[rec[i] & 511], 1);
    __syncthreads();
    if (t < NPB) lsc[t] = lh[t];
    __syncthreads();
    #pragma unroll
    for (int d = 1; d < NPB; d <<= 1) {
        int v = 0;
        if (t < NPB && t >= d) v = lsc[t - d];
        __syncthreads();
        if (t < NPB) lsc[t] += v;
        __syncthreads();
    }
    if (t < NPB) {
        int node = b * NPB + t;
        if (node < NNODES) {
            int ex = lsc[t] - lh[t];
            rowptr[node] = lo + ex;
            dinv[node] = rsqrtf((float)lh[t] + 1.0f);
        }
    }
    if (b == NB - 1 && t == 0) rowptr[NNODES] = NEDGES;
    __syncthreads();
    if (t < NPB) lsc[t] -= lh[t];   // exclusive -> cursor
    __syncthreads();
    for (int i = lo + t; i < hi; i += 1024) {
        unsigned r = rec[i];
        int dl = r & 511;
        int p = atomicAdd(&lsc[dl], 1);
        csr[lo + p] = (int)(r >> 9);
    }
}

// ---------------- layer-1 GEMM: g1 = fp16((x @ W1) * dinv[row]) ----------------
// Only W1 in LDS (32 KB, one barrier). Thread = 2 rows x 4 features; grid 1563
// (~6 blocks/CU, LDS-capped at 5 -> ~20 waves/CU latency hiding).

__global__ __launch_bounds__(256) void k_gemm1(
        const float* __restrict__ x, const float* __restrict__ W1,
        const float* __restrict__ dinv, __half2* __restrict__ g1) {
    __shared__ float Wl[F_IN * F_HID];    // [k][f], 32 KB
    int t = threadIdx.x;
    for (int i = t; i < (F_IN * F_HID) / 4; i += 256)
        ((float4*)Wl)[i] = ((const float4*)W1)[i];
    __syncthreads();

    int fg = (t & 7) * 4;
    int rg = (t >> 3) * 2;                // 0..62
    int row0 = blockIdx.x * GR + rg;

    const float* xr0 = x + (size_t)min(row0 + 0, NNODES - 1) * F_IN;
    const float* xr1 = x + (size_t)min(row0 + 1, NNODES - 1) * F_IN;

    float acc[2][4] = {};
    #pragma unroll 4
    for (int k = 0; k < F_IN; k += 4) {
        float4 xv0 = *(const float4*)&xr0[k];
        float4 xv1 = *(const float4*)&xr1[k];
        #pragma unroll
        for (int kk = 0; kk < 4; ++kk) {
            float4 wv = *(const float4*)&Wl[(k + kk) * F_HID + fg];
            float xs0 = (&xv0.x)[kk], xs1 = (&xv1.x)[kk];
            acc[0][0] = fmaf(xs0, wv.x, acc[0][0]);
            acc[0][1] = fmaf(xs0, wv.y, acc[0][1]);
            acc[0][2] = fmaf(xs0, wv.z, acc[0][2]);
            acc[0][3] = fmaf(xs0, wv.w, acc[0][3]);
            acc[1][0] = fmaf(xs1, wv.x, acc[1][0]);
            acc[1][1] = fmaf(xs1, wv.y, acc[1][1]);
            acc[1][2] = fmaf(xs1, wv.z, acc[1][2]);
            acc[1][3] = fmaf(xs1, wv.w, acc[1][3]);
        }
    }
    #pragma unroll
    for (int j = 0; j < 2; ++j) {
        int row = row0 + j;
        if (row < NNODES) {
            float dv = dinv[row];
            __half2 ha = __floats2half2_rn(acc[j][0] * dv, acc[j][1] * dv);
            __half2 hb = __floats2half2_rn(acc[j][2] * dv, acc[j][3] * dv);
            g1[(size_t)row * 16 + (fg >> 1)]     = ha;
            g1[(size_t)row * 16 + (fg >> 1) + 1] = hb;
        }
    }
}

// ---------------- gather layer 1 (fp16 rows; fused relu + [Wm|Wv]) ----------------

__global__ __launch_bounds__(256) void k_gather_l1(
        const int* __restrict__ rowptr, const int* __restrict__ csr,
        const float* __restrict__ dinv, const __half2* __restrict__ g,
        const float* __restrict__ b1, const float* __restrict__ Wm,
        const float* __restrict__ Wv, __half2* __restrict__ g2) {
    __shared__ float Wcat[F_HID * 32];
    __shared__ float hrow[16][F_HID + 2];
    int tx = threadIdx.x;
    for (int idx = tx; idx < F_HID * 32; idx += 256) {
        int k = idx >> 5, j = idx & 31;
        Wcat[idx] = (j < F_OUT) ? Wm[k * F_OUT + j] : Wv[k * F_OUT + (j - F_OUT)];
    }
    int f2 = tx & 15;                    // feature pair
    int lr = tx >> 4;                    // 0..15 local node
    int node = blockIdx.x * 16 + lr;
    int start = rowptr[node], end = rowptr[node + 1];
    float2 acc = __half22float2(g[(size_t)node * 16 + f2]);   // self loop
    int j = start;
    for (; j + 4 <= end; j += 4) {
        int s0 = csr[j], s1 = csr[j + 1], s2 = csr[j + 2], s3 = csr[j + 3];
        float2 a0 = __half22float2(g[(size_t)s0 * 16 + f2]);
        float2 a1 = __half22float2(g[(size_t)s1 * 16 + f2]);
        float2 a2 = __half22float2(g[(size_t)s2 * 16 + f2]);
        float2 a3 = __half22float2(g[(size_t)s3 * 16 + f2]);
        acc.x += (a0.x + a1.x) + (a2.x + a3.x);
        acc.y += (a0.y + a1.y) + (a2.y + a3.y);
    }
    for (; j < end; ++j) {
        float2 a = __half22float2(g[(size_t)csr[j] * 16 + f2]);
        acc.x += a.x; acc.y += a.y;
    }
    float dv = dinv[node];
    float h0 = dv * acc.x + b1[2 * f2];
    float h1 = dv * acc.y + b1[2 * f2 + 1];
    hrow[lr][2 * f2]     = h0 > 0.f ? h0 : 0.f;
    hrow[lr][2 * f2 + 1] = h1 > 0.f ? h1 : 0.f;
    __syncthreads();
    float o0 = 0.f, o1 = 0.f;
    #pragma unroll
    for (int k = 0; k < F_HID; ++k) {
        float hv = hrow[lr][k];
        o0 = fmaf(hv, Wcat[k * 32 + 2 * f2], o0);
        o1 = fmaf(hv, Wcat[k * 32 + 2 * f2 + 1], o1);
    }
    g2[(size_t)node * 16 + f2] = __floats2half2_rn(o0 * dv, o1 * dv);
}

// ---------------- gather layer 2 (fp16 rows; fused bias + mu/sigma split) --------

__global__ __launch_bounds__(256) void k_gather_out(
        const int* __restrict__ rowptr, const int* __restrict__ csr,
        const float* __restrict__ dinv, const __half2* __restrict__ g,
        const float* __restrict__ bm, const float* __restrict__ bv,
        float* __restrict__ out) {
    int tx = threadIdx.x;
    int f2 = tx & 15;
    int node = blockIdx.x * 16 + (tx >> 4);
    int start = rowptr[node], end = rowptr[node + 1];
    float2 acc = __half22float2(g[(size_t)node * 16 + f2]);   // self loop
    int j = start;
    for (; j + 4 <= end; j += 4) {
        int s0 = csr[j], s1 = csr[j + 1], s2 = csr[j + 2], s3 = csr[j + 3];
        float2 a0 = __half22float2(g[(size_t)s0 * 16 + f2]);
        float2 a1 = __half22float2(g[(size_t)s1 * 16 + f2]);
        float2 a2 = __half22float2(g[(size_t)s2 * 16 + f2]);
        float2 a3 = __half22float2(g[(size_t)s3 * 16 + f2]);
        acc.x += (a0.x + a1.x) + (a2.x + a3.x);
        acc.y += (a0.y + a1.y) + (a2.y + a3.y);
    }
    for (; j < end; ++j) {
        float2 a = __half22float2(g[(size_t)csr[j] * 16 + f2]);
        acc.x += a.x; acc.y += a.y;
    }
    float dv = dinv[node];
    int f = 2 * f2;
    if (f < F_OUT) {
        float2 o = { dv * acc.x + bm[f], dv * acc.y + bm[f + 1] };
        *(float2*)&out[(size_t)node * F_OUT + f] = o;
    } else {
        float2 o = { dv * acc.x + bv[f - F_OUT], dv * acc.y + bv[f - F_OUT + 1] };
        *(float2*)&out[(size_t)NNODES * F_OUT + (size_t)node * F_OUT + (f - F_OUT)] = o;
    }
}

// ---------------- launch ----------------

extern "C" void kernel_launch(void* const* d_in, const int* in_sizes, int n_in,
                              void* d_out, int out_size, void* d_ws, size_t ws_size,
                              hipStream_t stream) {
    const float* x   = (const float*)d_in[0];
    const int*   ei  = (const int*)  d_in[1];
    const float* W1  = (const float*)d_in[2];
    const float* b1  = (const float*)d_in[3];
    const float* Wm  = (const float*)d_in[4];
    const float* bm  = (const float*)d_in[5];
    const float* Wv  = (const float*)d_in[6];
    const float* bv  = (const float*)d_in[7];
    float* out = (float*)d_out;

    const int* src = ei;
    const int* dst = ei + NEDGES;

    // workspace (4B units):
    char* ws = (char*)d_ws;
    float*        dinv   = (float*)ws;        ws += 100352 * 4;
    int*          bhist  = (int*)ws;          ws += 256 * 4;
    int*          bbase  = (int*)ws;          ws += 256 * 4;
    int*          bcur   = (int*)ws;          ws += 256 * 4;
    int*          rowptr = (int*)ws;          ws += 100352 * 4;   // NNODES+1
    int*          csr    = (int*)ws;          ws += (size_t)NEDGES * 4;
    unsigned int* rec    = (unsigned int*)ws; ws += (size_t)NEDGES * 4;
    __half2*      g2     = (__half2*)ws;

    __half2* g1 = (__half2*)rec;   // rec dead after k_phaseB; gemm1 runs after

    // CSR build (bucketed counting sort)
    k_init  <<<1, 256, 0, stream>>>(bhist);
    k_bhist <<<256, 256, 0, stream>>>(dst, bhist);
    k_bscan <<<1, 256, 0, stream>>>(bhist, bbase, bcur);
    k_phaseA<<<NCHUNK, 256, 0, stream>>>(src, dst, bcur, rec);
    k_phaseB<<<NB, 1024, 0, stream>>>(rec, bbase, rowptr, dinv, csr);

    // layer 1 GEMM
    k_gemm1<<<GRID1, 256, 0, stream>>>(x, W1, dinv, g1);

    // gather 1 + relu + second transform (mu|sigma fused)
    k_gather_l1<<<NNODES / 16, 256, 0, stream>>>(rowptr, csr, dinv, g1, b1, Wm, Wv, g2);

    // gather 2 + bias + split to out
    k_gather_out<<<NNODES / 16, 256, 0, stream>>>(rowptr, csr, dinv, g2, bm, bv, out);
}

// Round 8
// 382.186 us; speedup vs baseline: 3.0151x; 1.0312x over previous
//
#include <hip/hip_runtime.h>
#include <hip/hip_fp16.h>

#define NNODES 100000
#define NEDGES 3200000
#define F_IN   256
#define F_HID  32
#define F_OUT  16

#define NB   196      // ceil(100000/512) buckets of 512 nodes
#define NPB  512      // nodes per bucket
#define NCHUNK 256    // phase-A blocks
#define CHUNK  12500  // edges per phase-A block (256*12500 = 3.2M exact)

#define GRID1 ((NNODES + 63) / 64)   // 1563 blocks, 64 rows/block (16/wave)

typedef _Float16 half_t;
typedef half_t half8 __attribute__((ext_vector_type(8)));
typedef float f32x4 __attribute__((ext_vector_type(4)));

// ---------------- bucketed CSR build ----------------

__global__ void k_init(int* __restrict__ bhist) {
    if (threadIdx.x < NB) bhist[threadIdx.x] = 0;
}

__global__ __launch_bounds__(256) void k_bhist(const int* __restrict__ dst,
                                               int* __restrict__ bhist) {
    __shared__ int lh[NB];
    int t = threadIdx.x;
    for (int i = t; i < NB; i += 256) lh[i] = 0;
    __syncthreads();
    for (int i = blockIdx.x * 256 + t; i < NEDGES; i += gridDim.x * 256)
        atomicAdd(&lh[dst[i] >> 9], 1);
    __syncthreads();
    for (int i = t; i < NB; i += 256)
        if (lh[i]) atomicAdd(&bhist[i], lh[i]);
}

__global__ __launch_bounds__(256) void k_bscan(const int* __restrict__ bhist,
                                               int* __restrict__ bbase,
                                               int* __restrict__ bcur) {
    __shared__ int s[256];
    int t = threadIdx.x;
    int my = (t < NB) ? bhist[t] : 0;
    s[t] = my;
    __syncthreads();
    #pragma unroll
    for (int d = 1; d < 256; d <<= 1) {
        int v = (t >= d) ? s[t - d] : 0;
        __syncthreads();
        s[t] += v;
        __syncthreads();
    }
    if (t < NB) {
        int ex = s[t] - my;
        bbase[t] = ex;
        bcur[t]  = ex;
        if (t == NB - 1) bbase[NB] = s[t];   // = NEDGES
    }
}

// Phase A: partition edges into bucket regions as packed records (src<<9)|dstLocal.
__global__ __launch_bounds__(256) void k_phaseA(
        const int* __restrict__ src, const int* __restrict__ dst,
        int* __restrict__ bcur, unsigned int* __restrict__ rec) {
    __shared__ int lh[NB];
    __shared__ int lcur[NB];
    int t = threadIdx.x;
    int e0 = blockIdx.x * CHUNK;
    for (int i = t; i < NB; i += 256) lh[i] = 0;
    __syncthreads();
    for (int i = t; i < CHUNK; i += 256)
        atomicAdd(&lh[dst[e0 + i] >> 9], 1);
    __syncthreads();
    for (int i = t; i < NB; i += 256)
        lcur[i] = lh[i] ? atomicAdd(&bcur[i], lh[i]) : 0;
    __syncthreads();
    for (int i = t; i < CHUNK; i += 256) {
        int s = src[e0 + i], d = dst[e0 + i];
        int b = d >> 9;
        int pos = atomicAdd(&lcur[b], 1);
        rec[pos] = ((unsigned)s << 9) | (unsigned)(d & 511);
    }
}

// Phase B: one block per bucket: per-node hist -> rowptr + dinv, then place.
__global__ __launch_bounds__(1024) void k_phaseB(
        const unsigned int* __restrict__ rec, const int* __restrict__ bbase,
        int* __restrict__ rowptr, float* __restrict__ dinv, int* __restrict__ csr) {
    __shared__ int lh[NPB];
    __shared__ int lsc[NPB];
    int t = threadIdx.x, b = blockIdx.x;
    int lo = bbase[b], hi = bbase[b + 1];
    for (int i = t; i < NPB; i += 1024) lh[i] = 0;
    __syncthreads();
    for (int i = lo + t; i < hi; i += 1024)
        atomicAdd(&lh[rec[i] & 511], 1);
    __syncthreads();
    if (t < NPB) lsc[t] = lh[t];
    __syncthreads();
    #pragma unroll
    for (int d = 1; d < NPB; d <<= 1) {
        int v = 0;
        if (t < NPB && t >= d) v = lsc[t - d];
        __syncthreads();
        if (t < NPB) lsc[t] += v;
        __syncthreads();
    }
    if (t < NPB) {
        int node = b * NPB + t;
        if (node < NNODES) {
            int ex = lsc[t] - lh[t];
            rowptr[node] = lo + ex;
            dinv[node] = rsqrtf((float)lh[t] + 1.0f);
        }
    }
    if (b == NB - 1 && t == 0) rowptr[NNODES] = NEDGES;
    __syncthreads();
    if (t < NPB) lsc[t] -= lh[t];   // exclusive -> cursor
    __syncthreads();
    for (int i = lo + t; i < hi; i += 1024) {
        unsigned r = rec[i];
        int dl = r & 511;
        int p = atomicAdd(&lsc[dl], 1);
        csr[lo + p] = (int)(r >> 9);
    }
}

// ---------------- layer-1 GEMM via MFMA: g1 = fp16((x @ W1) * dinv[row]) --------
// One wave = 16 rows x 32 cols over K=256: 16x mfma_f32_16x16x32_f16.
// A loaded straight from global in fragment order (lane: row=lane&15,
// k=quad*8+j, 8 contiguous fp32 -> cvt fp16). B (W1) loaded once per wave.
// C layout (verified): col=lane&15, row=quad*4+reg. Epilogue: dinv scale ->
// LDS repack (stride 33, conflict-free) -> coalesced half2 stores.

__global__ __launch_bounds__(256) void k_gemm1(
        const float* __restrict__ x, const float* __restrict__ W1,
        const float* __restrict__ dinv, __half2* __restrict__ g1) {
    __shared__ float sbuf[4][16 * 33];    // per-wave repack buffer, 8.4 KB
    int t = threadIdx.x;
    int wave = t >> 6, lane = t & 63;
    int m = lane & 15, q = lane >> 4;     // row-in-tile, quad

    int row0 = blockIdx.x * 64 + wave * 16;

    // B fragments: B[ft][kc][j] = W1[kc*32 + q*8 + j][ft*16 + m] as fp16
    half8 B[2][8];
    #pragma unroll
    for (int kc = 0; kc < 8; ++kc) {
        #pragma unroll
        for (int j = 0; j < 8; ++j) {
            int k = kc * 32 + q * 8 + j;
            B[0][kc][j] = (half_t)W1[k * F_HID + m];
            B[1][kc][j] = (half_t)W1[k * F_HID + 16 + m];
        }
    }

    int row = row0 + m; if (row >= NNODES) row = NNODES - 1;
    const float* xr = x + (size_t)row * F_IN;

    f32x4 acc0 = {0.f, 0.f, 0.f, 0.f};
    f32x4 acc1 = {0.f, 0.f, 0.f, 0.f};
    #pragma unroll
    for (int kc = 0; kc < 8; ++kc) {
        int k = kc * 32 + q * 8;
        float4 xa = *(const float4*)&xr[k];
        float4 xb = *(const float4*)&xr[k + 4];
        half8 A;
        A[0] = (half_t)xa.x; A[1] = (half_t)xa.y;
        A[2] = (half_t)xa.z; A[3] = (half_t)xa.w;
        A[4] = (half_t)xb.x; A[5] = (half_t)xb.y;
        A[6] = (half_t)xb.z; A[7] = (half_t)xb.w;
        acc0 = __builtin_amdgcn_mfma_f32_16x16x32_f16(A, B[0][kc], acc0, 0, 0, 0);
        acc1 = __builtin_amdgcn_mfma_f32_16x16x32_f16(A, B[1][kc], acc1, 0, 0, 0);
    }

    // scale by dinv and stash in LDS (row stride 33 -> write conflict-free)
    #pragma unroll
    for (int r = 0; r < 4; ++r) {
        int rl = q * 4 + r;
        int grow = row0 + rl; if (grow >= NNODES) grow = NNODES - 1;
        float dv = dinv[grow];
        sbuf[wave][rl * 33 + m]      = acc0[r] * dv;
        sbuf[wave][rl * 33 + 16 + m] = acc1[r] * dv;
    }
    __syncthreads();

    // repack: thread t -> row t>>2, cols (t&3)*8 .. +7 -> 4 half2 (8B) store
    int rl  = (t >> 2) & 15;
    int w2  = t >> 6;
    int c0  = (t & 3) * 8;
    int grow = blockIdx.x * 64 + w2 * 16 + rl;
    if (grow < NNODES) {
        const float* sp = &sbuf[w2][rl * 33 + c0];
        __half2 h0 = __floats2half2_rn(sp[0], sp[1]);
        __half2 h1 = __floats2half2_rn(sp[2], sp[3]);
        __half2 h2 = __floats2half2_rn(sp[4], sp[5]);
        __half2 h3 = __floats2half2_rn(sp[6], sp[7]);
        __half2* gp = &g1[(size_t)grow * 16 + (c0 >> 1)];
        gp[0] = h0; gp[1] = h1; gp[2] = h2; gp[3] = h3;
    }
}

// ---------------- gather layer 1 (fp16 rows; fused relu + [Wm|Wv]) ----------------

__global__ __launch_bounds__(256) void k_gather_l1(
        const int* __restrict__ rowptr, const int* __restrict__ csr,
        const float* __restrict__ dinv, const __half2* __restrict__ g,
        const float* __restrict__ b1, const float* __restrict__ Wm,
        const float* __restrict__ Wv, __half2* __restrict__ g2) {
    __shared__ float Wcat[F_HID * 32];
    __shared__ float hrow[16][F_HID + 2];
    int tx = threadIdx.x;
    for (int idx = tx; idx < F_HID * 32; idx += 256) {
        int k = idx >> 5, j = idx & 31;
        Wcat[idx] = (j < F_OUT) ? Wm[k * F_OUT + j] : Wv[k * F_OUT + (j - F_OUT)];
    }
    int f2 = tx & 15;                    // feature pair
    int lr = tx >> 4;                    // 0..15 local node
    int node = blockIdx.x * 16 + lr;
    int start = rowptr[node], end = rowptr[node + 1];
    float2 acc = __half22float2(g[(size_t)node * 16 + f2]);   // self loop
    int j = start;
    for (; j + 4 <= end; j += 4) {
        int s0 = csr[j], s1 = csr[j + 1], s2 = csr[j + 2], s3 = csr[j + 3];
        float2 a0 = __half22float2(g[(size_t)s0 * 16 + f2]);
        float2 a1 = __half22float2(g[(size_t)s1 * 16 + f2]);
        float2 a2 = __half22float2(g[(size_t)s2 * 16 + f2]);
        float2 a3 = __half22float2(g[(size_t)s3 * 16 + f2]);
        acc.x += (a0.x + a1.x) + (a2.x + a3.x);
        acc.y += (a0.y + a1.y) + (a2.y + a3.y);
    }
    for (; j < end; ++j) {
        float2 a = __half22float2(g[(size_t)csr[j] * 16 + f2]);
        acc.x += a.x; acc.y += a.y;
    }
    float dv = dinv[node];
    float h0 = dv * acc.x + b1[2 * f2];
    float h1 = dv * acc.y + b1[2 * f2 + 1];
    hrow[lr][2 * f2]     = h0 > 0.f ? h0 : 0.f;
    hrow[lr][2 * f2 + 1] = h1 > 0.f ? h1 : 0.f;
    __syncthreads();
    float o0 = 0.f, o1 = 0.f;
    #pragma unroll
    for (int k = 0; k < F_HID; ++k) {
        float hv = hrow[lr][k];
        o0 = fmaf(hv, Wcat[k * 32 + 2 * f2], o0);
        o1 = fmaf(hv, Wcat[k * 32 + 2 * f2 + 1], o1);
    }
    g2[(size_t)node * 16 + f2] = __floats2half2_rn(o0 * dv, o1 * dv);
}

// ---------------- gather layer 2 (fp16 rows; fused bias + mu/sigma split) --------

__global__ __launch_bounds__(256) void k_gather_out(
        const int* __restrict__ rowptr, const int* __restrict__ csr,
        const float* __restrict__ dinv, const __half2* __restrict__ g,
        const float* __restrict__ bm, const float* __restrict__ bv,
        float* __restrict__ out) {
    int tx = threadIdx.x;
    int f2 = tx & 15;
    int node = blockIdx.x * 16 + (tx >> 4);
    int start = rowptr[node], end = rowptr[node + 1];
    float2 acc = __half22float2(g[(size_t)node * 16 + f2]);   // self loop
    int j = start;
    for (; j + 4 <= end; j += 4) {
        int s0 = csr[j], s1 = csr[j + 1], s2 = csr[j + 2], s3 = csr[j + 3];
        float2 a0 = __half22float2(g[(size_t)s0 * 16 + f2]);
        float2 a1 = __half22float2(g[(size_t)s1 * 16 + f2]);
        float2 a2 = __half22float2(g[(size_t)s2 * 16 + f2]);
        float2 a3 = __half22float2(g[(size_t)s3 * 16 + f2]);
        acc.x += (a0.x + a1.x) + (a2.x + a3.x);
        acc.y += (a0.y + a1.y) + (a2.y + a3.y);
    }
    for (; j < end; ++j) {
        float2 a = __half22float2(g[(size_t)csr[j] * 16 + f2]);
        acc.x += a.x; acc.y += a.y;
    }
    float dv = dinv[node];
    int f = 2 * f2;
    if (f < F_OUT) {
        float2 o = { dv * acc.x + bm[f], dv * acc.y + bm[f + 1] };
        *(float2*)&out[(size_t)node * F_OUT + f] = o;
    } else {
        float2 o = { dv * acc.x + bv[f - F_OUT], dv * acc.y + bv[f - F_OUT + 1] };
        *(float2*)&out[(size_t)NNODES * F_OUT + (size_t)node * F_OUT + (f - F_OUT)] = o;
    }
}

// ---------------- launch ----------------

extern "C" void kernel_launch(void* const* d_in, const int* in_sizes, int n_in,
                              void* d_out, int out_size, void* d_ws, size_t ws_size,
                              hipStream_t stream) {
    const float* x   = (const float*)d_in[0];
    const int*   ei  = (const int*)  d_in[1];
    const float* W1  = (const float*)d_in[2];
    const float* b1  = (const float*)d_in[3];
    const float* Wm  = (const float*)d_in[4];
    const float* bm  = (const float*)d_in[5];
    const float* Wv  = (const float*)d_in[6];
    const float* bv  = (const float*)d_in[7];
    float* out = (float*)d_out;

    const int* src = ei;
    const int* dst = ei + NEDGES;

    // workspace (4B units):
    char* ws = (char*)d_ws;
    float*        dinv   = (float*)ws;        ws += 100352 * 4;
    int*          bhist  = (int*)ws;          ws += 256 * 4;
    int*          bbase  = (int*)ws;          ws += 256 * 4;
    int*          bcur   = (int*)ws;          ws += 256 * 4;
    int*          rowptr = (int*)ws;          ws += 100352 * 4;   // NNODES+1
    int*          csr    = (int*)ws;          ws += (size_t)NEDGES * 4;
    unsigned int* rec    = (unsigned int*)ws; ws += (size_t)NEDGES * 4;
    __half2*      g2     = (__half2*)ws;

    __half2* g1 = (__half2*)rec;   // rec dead after k_phaseB; gemm1 runs after

    // CSR build (bucketed counting sort)
    k_init  <<<1, 256, 0, stream>>>(bhist);
    k_bhist <<<256, 256, 0, stream>>>(dst, bhist);
    k_bscan <<<1, 256, 0, stream>>>(bhist, bbase, bcur);
    k_phaseA<<<NCHUNK, 256, 0, stream>>>(src, dst, bcur, rec);
    k_phaseB<<<NB, 1024, 0, stream>>>(rec, bbase, rowptr, dinv, csr);

    // layer 1 GEMM (MFMA)
    k_gemm1<<<GRID1, 256, 0, stream>>>(x, W1, dinv, g1);

    // gather 1 + relu + second transform (mu|sigma fused)
    k_gather_l1<<<NNODES / 16, 256, 0, stream>>>(rowptr, csr, dinv, g1, b1, Wm, Wv, g2);

    // gather 2 + bias + split to out
    k_gather_out<<<NNODES / 16, 256, 0, stream>>>(rowptr, csr, dinv, g2, bm, bv, out);
}

// Round 9
// 361.414 us; speedup vs baseline: 3.1884x; 1.0575x over previous
//
#include <hip/hip_runtime.h>
#include <hip/hip_fp16.h>

#define NNODES 100000
#define NEDGES 3200000
#define F_IN   256
#define F_HID  32
#define F_OUT  16

#define NB   196      // ceil(100000/512) buckets of 512 nodes
#define NPB  512      // nodes per bucket
#define CAP  20480    // fixed capacity per bucket region (mean 16327, +32 sigma)
#define NCHUNK 256    // phase-A blocks
#define CHUNK  12500  // edges per phase-A block

#define GRID1 ((NNODES + 63) / 64)   // 1563 blocks, 64 rows/block (16/wave)
#define XT_RS 130                    // xt row stride (floats): pad 2 -> 4-way max

typedef _Float16 half_t;
typedef half_t half8 __attribute__((ext_vector_type(8)));
typedef float f32x4 __attribute__((ext_vector_type(4)));
typedef const __attribute__((address_space(1))) unsigned int* gas_u32;
typedef __attribute__((address_space(3))) unsigned int* las_u32;

// ---------------- CSR build (fixed-capacity buckets) ----------------

__global__ void k_init(int* __restrict__ bcur) {
    if (threadIdx.x < NB) bcur[threadIdx.x] = threadIdx.x * CAP;
}

// Phase A: partition edges into bucket regions as packed records (src<<9)|dstLocal.
__global__ __launch_bounds__(256) void k_phaseA(
        const int* __restrict__ src, const int* __restrict__ dst,
        int* __restrict__ bcur, unsigned int* __restrict__ rec) {
    __shared__ int lh[NB];
    __shared__ int lcur[NB];
    int t = threadIdx.x;
    int e0 = blockIdx.x * CHUNK;
    for (int i = t; i < NB; i += 256) lh[i] = 0;
    __syncthreads();
    for (int i = t; i < CHUNK; i += 256)
        atomicAdd(&lh[dst[e0 + i] >> 9], 1);
    __syncthreads();
    for (int i = t; i < NB; i += 256)
        lcur[i] = lh[i] ? atomicAdd(&bcur[i], lh[i]) : 0;
    __syncthreads();
    for (int i = t; i < CHUNK; i += 256) {
        int s = src[e0 + i], d = dst[e0 + i];
        int b = d >> 9;
        int pos = atomicAdd(&lcur[b], 1);
        rec[pos] = ((unsigned)s << 9) | (unsigned)(d & 511);
    }
}

// Phase B: one block (512 thr) per bucket: hist -> shuffle scan -> rowptr/cnt/dinv,
// then place srcs into the bucket's csr region.
__global__ __launch_bounds__(512) void k_phaseB(
        const unsigned int* __restrict__ rec, const int* __restrict__ bcur,
        int* __restrict__ rowptr, int* __restrict__ cnt,
        float* __restrict__ dinv, int* __restrict__ csr) {
    __shared__ int lh[NPB];
    __shared__ int lsc[NPB];
    __shared__ int wsum[8];
    int t = threadIdx.x, b = blockIdx.x;
    int lo = b * CAP, hi = bcur[b];
    lh[t] = 0;
    __syncthreads();
    for (int i = lo + t; i < hi; i += 512)
        atomicAdd(&lh[rec[i] & 511], 1);
    __syncthreads();
    int lane = t & 63, w = t >> 6;
    int my = lh[t];
    int v = my;
    #pragma unroll
    for (int d = 1; d < 64; d <<= 1) {
        int tmp = __shfl_up(v, d, 64);
        if (lane >= d) v += tmp;
    }
    if (lane == 63) wsum[w] = v;
    __syncthreads();
    if (w == 0) {
        int s = (lane < 8) ? wsum[lane] : 0;
        #pragma unroll
        for (int d = 1; d < 8; d <<= 1) {
            int tmp = __shfl_up(s, d, 64);
            if (lane >= d) s += tmp;
        }
        if (lane < 8) wsum[lane] = s;
    }
    __syncthreads();
    int ex = v + (w > 0 ? wsum[w - 1] : 0) - my;   // exclusive
    lsc[t] = ex;
    int node = b * NPB + t;
    if (node < NNODES) {
        rowptr[node] = lo + ex;
        cnt[node] = my;
        dinv[node] = rsqrtf((float)my + 1.0f);
    }
    __syncthreads();
    for (int i = lo + t; i < hi; i += 512) {
        unsigned r = rec[i];
        int dl = r & 511;
        int p = atomicAdd(&lsc[dl], 1);
        csr[lo + p] = (int)(r >> 9);
    }
}

// ---------------- layer-1 GEMM via MFMA + async LDS staging ----------------
// Wt: W1 transposed to fp16 in LDS once -> B frags via 16 ds_read_b128 (one-time).
// A: per-wave 16x128 fp32 tile staged with global_load_lds (coalesced 256B chunks),
// stride-130 rows; fragments read as 4x float2 (8B aligned, ~4-way max conflict).
// No block barriers in the K-loop; epilogue reuses xt as repack buffer.

__global__ __launch_bounds__(256) void k_gemm1(
        const float* __restrict__ x, const float* __restrict__ W1,
        const float* __restrict__ dinv, __half2* __restrict__ g1) {
    __shared__ half_t Wt[32 * 264];       // [f][k] fp16, 16.9 KB
    __shared__ float xt[4][16 * XT_RS];   // per-wave A staging, 33.3 KB
    int t = threadIdx.x;
    int wave = t >> 6, lane = t & 63;
    int m = lane & 15, q = lane >> 4;
    int row0 = blockIdx.x * 64 + wave * 16;

    for (int i = t; i < F_IN * F_HID; i += 256) {
        int k = i >> 5, f = i & 31;
        Wt[f * 264 + k] = (half_t)W1[i];
    }
    __syncthreads();

    half8 B[2][8];
    #pragma unroll
    for (int ft = 0; ft < 2; ++ft)
        #pragma unroll
        for (int kc = 0; kc < 8; ++kc)
            B[ft][kc] = *(const half8*)&Wt[(ft * 16 + m) * 264 + kc * 32 + q * 8];

    float* xw = xt[wave];
    f32x4 acc0 = {0.f, 0.f, 0.f, 0.f};
    f32x4 acc1 = {0.f, 0.f, 0.f, 0.f};
    #pragma unroll
    for (int kh = 0; kh < 2; ++kh) {
        #pragma unroll
        for (int r = 0; r < 16; ++r) {
            int grow = row0 + r; if (grow >= NNODES) grow = NNODES - 1;
            const float* gp = &x[(size_t)grow * F_IN + kh * 128 + lane];
            __builtin_amdgcn_global_load_lds((gas_u32)gp,
                (las_u32)&xw[r * XT_RS], 4, 0, 0);
            __builtin_amdgcn_global_load_lds((gas_u32)(gp + 64),
                (las_u32)&xw[r * XT_RS + 64], 4, 0, 0);
        }
        asm volatile("s_waitcnt vmcnt(0)" ::: "memory");
        #pragma unroll
        for (int kc = 0; kc < 4; ++kc) {
            const float* sp = &xw[m * XT_RS + kc * 32 + q * 8];
            float2 x0 = *(const float2*)sp;
            float2 x1 = *(const float2*)(sp + 2);
            float2 x2 = *(const float2*)(sp + 4);
            float2 x3 = *(const float2*)(sp + 6);
            half8 A;
            A[0] = (half_t)x0.x; A[1] = (half_t)x0.y;
            A[2] = (half_t)x1.x; A[3] = (half_t)x1.y;
            A[4] = (half_t)x2.x; A[5] = (half_t)x2.y;
            A[6] = (half_t)x3.x; A[7] = (half_t)x3.y;
            acc0 = __builtin_amdgcn_mfma_f32_16x16x32_f16(A, B[0][kh * 4 + kc], acc0, 0, 0, 0);
            acc1 = __builtin_amdgcn_mfma_f32_16x16x32_f16(A, B[1][kh * 4 + kc], acc1, 0, 0, 0);
        }
        if (kh == 0) asm volatile("s_waitcnt lgkmcnt(0)" ::: "memory");
    }

    // epilogue: dinv scale -> repack via xt (stride 33) -> coalesced half2 stores
    __syncthreads();
    float* sb = xw;
    #pragma unroll
    for (int r = 0; r < 4; ++r) {
        int rl = q * 4 + r;
        int grow = row0 + rl; if (grow >= NNODES) grow = NNODES - 1;
        float dv = dinv[grow];
        sb[rl * 33 + m]      = acc0[r] * dv;
        sb[rl * 33 + 16 + m] = acc1[r] * dv;
    }
    __syncthreads();
    int rl = (t >> 2) & 15;
    int w2 = t >> 6;
    int c0 = (t & 3) * 8;
    int grow = blockIdx.x * 64 + w2 * 16 + rl;
    if (grow < NNODES) {
        const float* sp = &xt[w2][rl * 33 + c0];
        __half2 h0 = __floats2half2_rn(sp[0], sp[1]);
        __half2 h1 = __floats2half2_rn(sp[2], sp[3]);
        __half2 h2 = __floats2half2_rn(sp[4], sp[5]);
        __half2 h3 = __floats2half2_rn(sp[6], sp[7]);
        __half2* gp = &g1[(size_t)grow * 16 + (c0 >> 1)];
        gp[0] = h0; gp[1] = h1; gp[2] = h2; gp[3] = h3;
    }
}

// ---------------- gather layer 1 (fp16 rows; fused relu + [Wm|Wv]) ----------------

__global__ __launch_bounds__(256) void k_gather_l1(
        const int* __restrict__ rowptr, const int* __restrict__ cnt,
        const int* __restrict__ csr,
        const float* __restrict__ dinv, const __half2* __restrict__ g,
        const float* __restrict__ b1, const float* __restrict__ Wm,
        const float* __restrict__ Wv, __half2* __restrict__ g2) {
    __shared__ float Wcat[F_HID * 32];
    __shared__ float hrow[16][F_HID + 2];
    int tx = threadIdx.x;
    for (int idx = tx; idx < F_HID * 32; idx += 256) {
        int k = idx >> 5, j = idx & 31;
        Wcat[idx] = (j < F_OUT) ? Wm[k * F_OUT + j] : Wv[k * F_OUT + (j - F_OUT)];
    }
    int f2 = tx & 15;
    int lr = tx >> 4;
    int node = blockIdx.x * 16 + lr;
    int start = rowptr[node], end = start + cnt[node];
    float2 acc = __half22float2(g[(size_t)node * 16 + f2]);   // self loop
    int j = start;
    for (; j + 4 <= end; j += 4) {
        int s0 = csr[j], s1 = csr[j + 1], s2 = csr[j + 2], s3 = csr[j + 3];
        float2 a0 = __half22float2(g[(size_t)s0 * 16 + f2]);
        float2 a1 = __half22float2(g[(size_t)s1 * 16 + f2]);
        float2 a2 = __half22float2(g[(size_t)s2 * 16 + f2]);
        float2 a3 = __half22float2(g[(size_t)s3 * 16 + f2]);
        acc.x += (a0.x + a1.x) + (a2.x + a3.x);
        acc.y += (a0.y + a1.y) + (a2.y + a3.y);
    }
    for (; j < end; ++j) {
        float2 a = __half22float2(g[(size_t)csr[j] * 16 + f2]);
        acc.x += a.x; acc.y += a.y;
    }
    float dv = dinv[node];
    float h0 = dv * acc.x + b1[2 * f2];
    float h1 = dv * acc.y + b1[2 * f2 + 1];
    hrow[lr][2 * f2]     = h0 > 0.f ? h0 : 0.f;
    hrow[lr][2 * f2 + 1] = h1 > 0.f ? h1 : 0.f;
    __syncthreads();
    float o0 = 0.f, o1 = 0.f;
    #pragma unroll
    for (int k = 0; k < F_HID; ++k) {
        float hv = hrow[lr][k];
        o0 = fmaf(hv, Wcat[k * 32 + 2 * f2], o0);
        o1 = fmaf(hv, Wcat[k * 32 + 2 * f2 + 1], o1);
    }
    g2[(size_t)node * 16 + f2] = __floats2half2_rn(o0 * dv, o1 * dv);
}

// ---------------- gather layer 2 (fp16 rows; fused bias + mu/sigma split) --------

__global__ __launch_bounds__(256) void k_gather_out(
        const int* __restrict__ rowptr, const int* __restrict__ cnt,
        const int* __restrict__ csr,
        const float* __restrict__ dinv, const __half2* __restrict__ g,
        const float* __restrict__ bm, const float* __restrict__ bv,
        float* __restrict__ out) {
    int tx = threadIdx.x;
    int f2 = tx & 15;
    int node = blockIdx.x * 16 + (tx >> 4);
    int start = rowptr[node], end = start + cnt[node];
    float2 acc = __half22float2(g[(size_t)node * 16 + f2]);   // self loop
    int j = start;
    for (; j + 4 <= end; j += 4) {
        int s0 = csr[j], s1 = csr[j + 1], s2 = csr[j + 2], s3 = csr[j + 3];
        float2 a0 = __half22float2(g[(size_t)s0 * 16 + f2]);
        float2 a1 = __half22float2(g[(size_t)s1 * 16 + f2]);
        float2 a2 = __half22float2(g[(size_t)s2 * 16 + f2]);
        float2 a3 = __half22float2(g[(size_t)s3 * 16 + f2]);
        acc.x += (a0.x + a1.x) + (a2.x + a3.x);
        acc.y += (a0.y + a1.y) + (a2.y + a3.y);
    }
    for (; j < end; ++j) {
        float2 a = __half22float2(g[(size_t)csr[j] * 16 + f2]);
        acc.x += a.x; acc.y += a.y;
    }
    float dv = dinv[node];
    int f = 2 * f2;
    if (f < F_OUT) {
        float2 o = { dv * acc.x + bm[f], dv * acc.y + bm[f + 1] };
        *(float2*)&out[(size_t)node * F_OUT + f] = o;
    } else {
        float2 o = { dv * acc.x + bv[f - F_OUT], dv * acc.y + bv[f - F_OUT + 1] };
        *(float2*)&out[(size_t)NNODES * F_OUT + (size_t)node * F_OUT + (f - F_OUT)] = o;
    }
}

// ---------------- launch ----------------

extern "C" void kernel_launch(void* const* d_in, const int* in_sizes, int n_in,
                              void* d_out, int out_size, void* d_ws, size_t ws_size,
                              hipStream_t stream) {
    const float* x   = (const float*)d_in[0];
    const int*   ei  = (const int*)  d_in[1];
    const float* W1  = (const float*)d_in[2];
    const float* b1  = (const float*)d_in[3];
    const float* Wm  = (const float*)d_in[4];
    const float* bm  = (const float*)d_in[5];
    const float* Wv  = (const float*)d_in[6];
    const float* bv  = (const float*)d_in[7];
    float* out = (float*)d_out;

    const int* src = ei;
    const int* dst = ei + NEDGES;

    // workspace layout (4B units), ~40 MB:
    char* ws = (char*)d_ws;
    float*        dinv   = (float*)ws;        ws += 100352 * 4;
    int*          bcur   = (int*)ws;          ws += 256 * 4;
    int*          rowptr = (int*)ws;          ws += 100352 * 4;
    int*          cnt    = (int*)ws;          ws += 100352 * 4;
    int*          csr    = (int*)ws;          ws += (size_t)NB * CAP * 4;
    unsigned int* rec    = (unsigned int*)ws; ws += (size_t)NB * CAP * 4;
    __half2*      g2     = (__half2*)ws;

    __half2* g1 = (__half2*)rec;   // rec dead after k_phaseB

    // CSR build
    k_init  <<<1, 256, 0, stream>>>(bcur);
    k_phaseA<<<NCHUNK, 256, 0, stream>>>(src, dst, bcur, rec);
    k_phaseB<<<NB, 512, 0, stream>>>(rec, bcur, rowptr, cnt, dinv, csr);

    // layer 1 GEMM (MFMA, async LDS staging)
    k_gemm1<<<GRID1, 256, 0, stream>>>(x, W1, dinv, g1);

    // gather 1 + relu + second transform (mu|sigma fused)
    k_gather_l1<<<NNODES / 16, 256, 0, stream>>>(rowptr, cnt, csr, dinv, g1, b1, Wm, Wv, g2);

    // gather 2 + bias + split to out
    k_gather_out<<<NNODES / 16, 256, 0, stream>>>(rowptr, cnt, csr, dinv, g2, bm, bv, out);
}